// Round 14
// baseline (2394.832 us; speedup 1.0000x reference)
//
#include <hip/hip_runtime.h>
#include <hip/hip_bf16.h>
#include <math.h>

// Problem constants (match reference)
#define NB    4096   // num_batch
#define NV    120    // NVAR
#define NCN   240    // num constraints
#define HIDD  1024   // GRU hidden
#define RINN  1080   // GRU input dim
#define NOUTD 360    // NC+NVAR
#define NOUTP 384    // padded out cols
#define NITER 8
#define REGEPS 1e-4f
#define NPART 512    // Gram partials now emitted by k_xiproj (one per block)

// Precision scheme (round 14): weights bf16 (hi); GEMM consumes ONLY a_hi
// (activation bf16). h state still STORED as [hi|lo] so the recurrent
// carry h_new = (1-z)n + z*(h_hi+h_lo) stays near-f32 accurate.
// act row: [r_hi 1088 | r_lo 1088 | h_hi 1024 | h_lo 1024] = 4224
// Wcat row: [Wih_hi 1088 | Whh_hi 1024] = 2112
#define KCAT 4224
#define HOFF 2176    // h section start within an act row
#define KWC  2112    // Wcat K
#define KWO  1024    // W_out packed K
#define NSTEP_R 34   // r-section 32-wide K-steps (1088/32)
#define NSTEPS  66   // total (2112/32)

typedef unsigned short u16;
typedef __attribute__((ext_vector_type(8))) short short8v;
typedef __attribute__((ext_vector_type(4))) float f32x4;

__device__ inline u16 f2b(float x) {
    __hip_bfloat16 h = __float2bfloat16(x);
    return __builtin_bit_cast(u16, h);
}
__device__ inline float b2f(u16 u) {
    __hip_bfloat16 h = __builtin_bit_cast(__hip_bfloat16, u);
    return __bfloat162float(h);
}

// async global -> LDS, 16B per lane (wave-uniform LDS base + lane*16)
__device__ inline void gl16(const void* g, void* l) {
    __builtin_amdgcn_global_load_lds(
        (__attribute__((address_space(1))) void*)(void*)g,
        (__attribute__((address_space(3))) void*)l, 16, 0, 0);
}

// ---------------------------------------------------------------------------
// Build A = H + C^T C + REG*I (which==0) and A0 = H + REG*I (which==1)
__global__ void k_buildA(const float* __restrict__ H, const float* __restrict__ C,
                         float* __restrict__ A, float* __restrict__ A0) {
    int i = blockIdx.x;
    int which = blockIdx.y;
    for (int j = threadIdx.x; j < NV; j += blockDim.x) {
        float v = H[i*NV + j] + (i == j ? REGEPS : 0.f);
        if (which == 0) {
            float acc = 0.f;
            for (int k = 0; k < NCN; ++k) acc += C[k*NV + i] * C[k*NV + j];
            A[i*NV + j] = v + acc;   // RHO = 1
        } else {
            A0[i*NV + j] = v;
        }
    }
}

// CT[j][k] = C[k][j]
__global__ void k_buildCT(const float* __restrict__ C, float* __restrict__ CT) {
    int j = blockIdx.x;   // 0..119
    for (int k = threadIdx.x; k < NCN; k += 256)
        CT[(size_t)j * NCN + k] = C[(size_t)k * NV + j];
}

// Row-major 4x4 inverse via 2x2-subdeterminant adjugate (ILP-friendly).
__device__ inline void inv4x4(const float* m, float* inv) {
    float s0 = m[0]*m[5] - m[1]*m[4];
    float s1 = m[0]*m[6] - m[2]*m[4];
    float s2 = m[0]*m[7] - m[3]*m[4];
    float s3 = m[1]*m[6] - m[2]*m[5];
    float s4 = m[1]*m[7] - m[3]*m[5];
    float s5 = m[2]*m[7] - m[3]*m[6];
    float c5 = m[10]*m[15] - m[11]*m[14];
    float c4 = m[9]*m[15] - m[11]*m[13];
    float c3 = m[9]*m[14] - m[10]*m[13];
    float c2 = m[8]*m[15] - m[11]*m[12];
    float c1 = m[8]*m[14] - m[10]*m[12];
    float c0 = m[8]*m[13] - m[9]*m[12];
    float det = s0*c5 - s1*c4 + s2*c3 + s3*c2 - s4*c1 + s5*c0;
    float id = 1.0f / det;
    inv[0]  = ( m[5]*c5 - m[6]*c4 + m[7]*c3) * id;
    inv[1]  = (-m[1]*c5 + m[2]*c4 - m[3]*c3) * id;
    inv[2]  = ( m[13]*s5 - m[14]*s4 + m[15]*s3) * id;
    inv[3]  = (-m[9]*s5 + m[10]*s4 - m[11]*s3) * id;
    inv[4]  = (-m[4]*c5 + m[6]*c2 - m[7]*c1) * id;
    inv[5]  = ( m[0]*c5 - m[2]*c2 + m[3]*c1) * id;
    inv[6]  = (-m[12]*s5 + m[14]*s2 - m[15]*s1) * id;
    inv[7]  = ( m[8]*s5 - m[10]*s2 + m[11]*s1) * id;
    inv[8]  = ( m[4]*c4 - m[5]*c2 + m[7]*c0) * id;
    inv[9]  = (-m[0]*c4 + m[1]*c2 - m[3]*c0) * id;
    inv[10] = ( m[12]*s4 - m[13]*s2 + m[15]*s0) * id;
    inv[11] = (-m[8]*s4 + m[9]*s2 - m[11]*s0) * id;
    inv[12] = (-m[4]*c3 + m[5]*c1 - m[6]*c0) * id;
    inv[13] = ( m[0]*c3 - m[1]*c1 + m[2]*c0) * id;
    inv[14] = (-m[12]*s3 + m[13]*s1 - m[14]*s0) * id;
    inv[15] = ( m[8]*s3 - m[9]*s1 + m[10]*s0) * id;
}

// Blocked rank-4 Gauss-Jordan, phase-split. 2 barriers/chunk, 30 chunks.
__global__ __launch_bounds__(1024) void k_invert(const float* __restrict__ Ain,
                                                 const float* __restrict__ A0in,
                                                 float* __restrict__ Qi,
                                                 float* __restrict__ Qi0) {
    __shared__ float M[NV][132];
    __shared__ float Rl[4][132];
    __shared__ float Bl[16];
    const float* src = (blockIdx.x == 0) ? Ain : A0in;
    float* dst = (blockIdx.x == 0) ? Qi : Qi0;
    const int t = threadIdx.x;
    for (int idx = t; idx < NV*132; idx += 1024) {
        int i = idx / 132, j = idx - i*132;
        M[i][j] = (j < NV) ? src[i*NV + j] : 0.f;
    }
    __syncthreads();
    const int ty = t >> 5;        // 0..31 row owner (4 rows each)
    const int g4 = (t & 31) * 4;  // col group 0..124
    for (int kk = 0; kk < NV; kk += 4) {
        if (ty == 0) {
            float a[16], b[16];
            #pragma unroll
            for (int p = 0; p < 4; ++p) {
                float4 v = *(const float4*)&M[kk + p][kk];
                a[p*4+0] = v.x; a[p*4+1] = v.y; a[p*4+2] = v.z; a[p*4+3] = v.w;
            }
            inv4x4(a, b);
            float4 m0v = *(const float4*)&M[kk+0][g4];
            float4 m1v = *(const float4*)&M[kk+1][g4];
            float4 m2v = *(const float4*)&M[kk+2][g4];
            float4 m3v = *(const float4*)&M[kk+3][g4];
            #pragma unroll
            for (int p = 0; p < 4; ++p) {
                float4 r;
                r.x = b[p*4+0]*m0v.x + b[p*4+1]*m1v.x + b[p*4+2]*m2v.x + b[p*4+3]*m3v.x;
                r.y = b[p*4+0]*m0v.y + b[p*4+1]*m1v.y + b[p*4+2]*m2v.y + b[p*4+3]*m3v.y;
                r.z = b[p*4+0]*m0v.z + b[p*4+1]*m1v.z + b[p*4+2]*m2v.z + b[p*4+3]*m3v.z;
                r.w = b[p*4+0]*m0v.w + b[p*4+1]*m1v.w + b[p*4+2]*m2v.w + b[p*4+3]*m3v.w;
                *(float4*)&Rl[p][g4] = r;
            }
            if (t < 16) Bl[t] = b[t];
        }
        float4 F[4];
        #pragma unroll
        for (int q = 0; q < 4; ++q) {
            int i = ty + 32*q;
            F[q] = (i < NV) ? *(const float4*)&M[i][kk] : float4{0.f,0.f,0.f,0.f};
        }
        __syncthreads();
        #pragma unroll
        for (int q = 0; q < 4; ++q) {
            int i = ty + 32*q;
            if (i < NV) {
                int dp = i - kk;
                bool ispiv = (dp >= 0) && (dp < 4);
                float4 v;
                if (g4 == kk) {
                    if (ispiv) {
                        v = *(const float4*)&Bl[dp*4];
                    } else {
                        v.x = -(F[q].x*Bl[0] + F[q].y*Bl[4] + F[q].z*Bl[8]  + F[q].w*Bl[12]);
                        v.y = -(F[q].x*Bl[1] + F[q].y*Bl[5] + F[q].z*Bl[9]  + F[q].w*Bl[13]);
                        v.z = -(F[q].x*Bl[2] + F[q].y*Bl[6] + F[q].z*Bl[10] + F[q].w*Bl[14]);
                        v.w = -(F[q].x*Bl[3] + F[q].y*Bl[7] + F[q].z*Bl[11] + F[q].w*Bl[15]);
                    }
                } else if (ispiv) {
                    v = *(const float4*)&Rl[dp][g4];
                } else {
                    float4 r0 = *(const float4*)&Rl[0][g4];
                    float4 r1 = *(const float4*)&Rl[1][g4];
                    float4 r2 = *(const float4*)&Rl[2][g4];
                    float4 r3 = *(const float4*)&Rl[3][g4];
                    v = *(const float4*)&M[i][g4];
                    v.x -= F[q].x*r0.x + F[q].y*r1.x + F[q].z*r2.x + F[q].w*r3.x;
                    v.y -= F[q].x*r0.y + F[q].y*r1.y + F[q].z*r2.y + F[q].w*r3.y;
                    v.z -= F[q].x*r0.z + F[q].y*r1.z + F[q].z*r2.z + F[q].w*r3.z;
                    v.w -= F[q].x*r0.w + F[q].y*r1.w + F[q].z*r2.w + F[q].w*r3.w;
                }
                *(float4*)&M[i][g4] = v;
            }
        }
        __syncthreads();
    }
    for (int idx = t; idx < NV*NV; idx += 1024) {
        int i = idx / NV, j = idx - i*NV;
        dst[idx] = M[i][j];
    }
}

// xi0 = (-g) @ Qinv0^T ; s0 = max(0, c - C xi0)   (batch-constant vectors)
__global__ void k_s0(const float* __restrict__ Qi0, const float* __restrict__ g,
                     const float* __restrict__ C, const float* __restrict__ c,
                     float* __restrict__ s0v) {
    __shared__ float xi0[NV];
    int t = threadIdx.x;
    if (t < NV) {
        float a = 0.f;
        for (int j = 0; j < NV; ++j) a += Qi0[t*NV + j] * g[j];
        xi0[t] = -a;
    }
    __syncthreads();
    if (t < NCN) {
        float a = 0.f;
        for (int j = 0; j < NV; ++j) a += C[t*NV + j] * xi0[j];
        s0v[t] = fmaxf(0.f, c[t] - a);
    }
}

// Initialize state: s = broadcast(s0), lam = lamda_init
__global__ void k_init(const float* __restrict__ s0v, const float* __restrict__ lam0,
                       float* __restrict__ s, float* __restrict__ lam) {
    int b0 = blockIdx.x * 8;
    int t = threadIdx.x;
    for (int idx = t; idx < 8*NCN; idx += 256) {
        int m = idx / NCN, k = idx % NCN;
        s[(size_t)(b0 + m)*NCN + k] = s0v[k];
    }
    for (int idx = t; idx < 8*NV; idx += 256) lam[(size_t)b0*NV + idx] = lam0[(size_t)b0*NV + idx];
}

// Pack h0 into act buffer h-section: [h_hi | h_lo]
__global__ void k_packH(const float* __restrict__ h0, u16* __restrict__ act) {
    int n = blockIdx.x;
    size_t base = (size_t)n * KCAT + HOFF;
    for (int k = threadIdx.x; k < HIDD; k += 256) {
        float x = h0[(size_t)n * HIDD + k];
        u16 hi = f2b(x);
        act[base + k] = hi;
        act[base + HIDD + k] = f2b(x - b2f(hi));
    }
}

// Pack Wih+Whh (hi only, once): [Wih_hi 1088 | Whh_hi 1024]
__global__ void k_packWcat(const float* __restrict__ Wih, const float* __restrict__ Whh,
                           u16* __restrict__ Wc) {
    int n = blockIdx.x;   // 0..3071
    size_t base = (size_t)n * KWC;
    for (int k = threadIdx.x; k < 1088; k += 256)
        Wc[base + k] = f2b(k < RINN ? Wih[(size_t)n * RINN + k] : 0.f);
    for (int k = threadIdx.x; k < HIDD; k += 256)
        Wc[base + 1088 + k] = f2b(Whh[(size_t)n * HIDD + k]);
}

// Pack W_out (hi only): [NOUTP rows][1024]
__global__ void k_packWo(const float* __restrict__ src, u16* __restrict__ dst) {
    int n = blockIdx.x;
    size_t row = (size_t)n * KWO;
    for (int k = threadIdx.x; k < KWO; k += 256)
        dst[row + k] = f2b(n < NOUTD ? src[(size_t)n * HIDD + k] : 0.f);
}

__device__ inline void write2(u16* __restrict__ act, size_t base, int pos, float x) {
    u16 hi = f2b(x);
    u16 lo = f2b(x - b2f(hi));
    act[base + pos] = hi;
    act[base + 1088 + pos] = lo;
}

__device__ inline float hadd4(float4 v) { return (v.x + v.y) + (v.z + v.w); }

// ---------------------------------------------------------------------------
// Fused: xi solve + projection + GRU-input pack + Gram/v/S partials
// (k_qp_part is FUSED: xl is already in LDS at kernel end). 8 batches/block.
#define XB 8
__global__ __launch_bounds__(512) void k_xiproj(
        const float* __restrict__ s, const float* __restrict__ lam,
        const float* __restrict__ Cg, const float* __restrict__ CTg,
        const float* __restrict__ c,
        const float* __restrict__ g, const float* __restrict__ Qi,
        const float* __restrict__ Hg,
        float* __restrict__ xi, float* __restrict__ Y,
        float* __restrict__ snew, float* __restrict__ lamn,
        u16* __restrict__ act, float* __restrict__ primal,
        double* __restrict__ Gp, double* __restrict__ vp, double* __restrict__ Sp) {
    __shared__ float Msh[31680];      // C/QH: [240][132]; CT: [120][244]
    __shared__ float bd[XB][NCN];
    __shared__ float ul[XB][NV];
    __shared__ float xl[XB][NV];
    __shared__ float resl[XB][NCN];
    __shared__ float wl[XB];
    const int b0 = blockIdx.x * XB;
    const int t = threadIdx.x;

    // stage CT + bd
    for (int idx = t; idx < XB*NCN; idx += 512) {
        int m = idx / NCN, k = idx - m*NCN;
        bd[m][k] = c[k] - s[(size_t)(b0 + m)*NCN + k];
    }
    for (int idx = t; idx < NV*NCN; idx += 512) {
        int i = idx / NCN, k = idx - i*NCN;
        Msh[i*244 + k] = CTg[idx];
    }
    __syncthreads();
    // phase 2: ul_j = lam_j - g_j + sum_k bd_k CT[j][k]
    if (t < 240) {
        int m = t / 30, jb = t - (t / 30) * 30;
        float4 a0 = {0,0,0,0}, a1 = {0,0,0,0}, a2 = {0,0,0,0}, a3 = {0,0,0,0};
        for (int kg = 0; kg < 60; ++kg) {
            float4 b4 = *(const float4*)&bd[m][kg*4];
            float4 c0 = *(const float4*)&Msh[(jb     ) * 244 + kg*4];
            float4 c1 = *(const float4*)&Msh[(jb + 30) * 244 + kg*4];
            float4 c2 = *(const float4*)&Msh[(jb + 60) * 244 + kg*4];
            float4 c3 = *(const float4*)&Msh[(jb + 90) * 244 + kg*4];
            a0.x += b4.x*c0.x; a0.y += b4.y*c0.y; a0.z += b4.z*c0.z; a0.w += b4.w*c0.w;
            a1.x += b4.x*c1.x; a1.y += b4.y*c1.y; a1.z += b4.z*c1.z; a1.w += b4.w*c1.w;
            a2.x += b4.x*c2.x; a2.y += b4.y*c2.y; a2.z += b4.z*c2.z; a2.w += b4.w*c2.w;
            a3.x += b4.x*c3.x; a3.y += b4.y*c3.y; a3.z += b4.z*c3.z; a3.w += b4.w*c3.w;
        }
        #pragma unroll
        for (int p = 0; p < 4; ++p) {
            int j = jb + 30*p;
            float h = (p == 0) ? hadd4(a0) : (p == 1) ? hadd4(a1) : (p == 2) ? hadd4(a2) : hadd4(a3);
            ul[m][j] = lam[(size_t)(b0 + m)*NV + j] - g[j] + h;
        }
    }
    __syncthreads();
    // stage Qinv (rows 0..119) + H (rows 120..239), stride 132
    for (int idx = t; idx < NV*NV; idx += 512) {
        int i = idx / NV, j = idx - i*NV;
        Msh[i*132 + j] = Qi[idx];
        Msh[(120 + i)*132 + j] = Hg[idx];
    }
    __syncthreads();
    // phase 3: xi_i = sum_j Qinv[i][j] ul_j
    if (t < 240) {
        int m = t / 30, ib = t - (t / 30) * 30;
        float4 a0 = {0,0,0,0}, a1 = {0,0,0,0}, a2 = {0,0,0,0}, a3 = {0,0,0,0};
        for (int jg = 0; jg < 30; ++jg) {
            float4 u4 = *(const float4*)&ul[m][jg*4];
            float4 q0 = *(const float4*)&Msh[(ib     ) * 132 + jg*4];
            float4 q1 = *(const float4*)&Msh[(ib + 30) * 132 + jg*4];
            float4 q2 = *(const float4*)&Msh[(ib + 60) * 132 + jg*4];
            float4 q3 = *(const float4*)&Msh[(ib + 90) * 132 + jg*4];
            a0.x += u4.x*q0.x; a0.y += u4.y*q0.y; a0.z += u4.z*q0.z; a0.w += u4.w*q0.w;
            a1.x += u4.x*q1.x; a1.y += u4.y*q1.y; a1.z += u4.z*q1.z; a1.w += u4.w*q1.w;
            a2.x += u4.x*q2.x; a2.y += u4.y*q2.y; a2.z += u4.z*q2.z; a2.w += u4.w*q2.w;
            a3.x += u4.x*q3.x; a3.y += u4.y*q3.y; a3.z += u4.z*q3.z; a3.w += u4.w*q3.w;
        }
        #pragma unroll
        for (int p = 0; p < 4; ++p) {
            int i = ib + 30*p;
            float a = (p == 0) ? hadd4(a0) : (p == 1) ? hadd4(a1) : (p == 2) ? hadd4(a2) : hadd4(a3);
            xl[m][i] = a;
            xi[(size_t)(b0 + m)*NV + i] = a;
        }
    }
    __syncthreads();
    // phase 4: Y_i = sum_j xl_j H[i][j]; wl = xl . g
    if (t < 240) {
        int m = t / 30, ib = t - (t / 30) * 30;
        float4 a0 = {0,0,0,0}, a1 = {0,0,0,0}, a2 = {0,0,0,0}, a3 = {0,0,0,0};
        for (int jg = 0; jg < 30; ++jg) {
            float4 x4 = *(const float4*)&xl[m][jg*4];
            float4 h0 = *(const float4*)&Msh[(120 + ib     ) * 132 + jg*4];
            float4 h1 = *(const float4*)&Msh[(120 + ib + 30) * 132 + jg*4];
            float4 h2 = *(const float4*)&Msh[(120 + ib + 60) * 132 + jg*4];
            float4 h3 = *(const float4*)&Msh[(120 + ib + 90) * 132 + jg*4];
            a0.x += x4.x*h0.x; a0.y += x4.y*h0.y; a0.z += x4.z*h0.z; a0.w += x4.w*h0.w;
            a1.x += x4.x*h1.x; a1.y += x4.y*h1.y; a1.z += x4.z*h1.z; a1.w += x4.w*h1.w;
            a2.x += x4.x*h2.x; a2.y += x4.y*h2.y; a2.z += x4.z*h2.z; a2.w += x4.w*h2.w;
            a3.x += x4.x*h3.x; a3.y += x4.y*h3.y; a3.z += x4.z*h3.z; a3.w += x4.w*h3.w;
        }
        #pragma unroll
        for (int p = 0; p < 4; ++p) {
            int i = ib + 30*p;
            float a = (p == 0) ? hadd4(a0) : (p == 1) ? hadd4(a1) : (p == 2) ? hadd4(a2) : hadd4(a3);
            Y[(size_t)(b0 + m)*NV + i] = a;
        }
    }
    if (t >= 240 && t < 240 + XB) {
        int m = t - 240;
        float a = 0.f;
        for (int j = 0; j < NV; ++j) a += xl[m][j] * g[j];
        wl[m] = a;
    }
    __syncthreads();
    // stage C (rows 0..239, stride 132)
    for (int idx = t; idx < NCN*NV; idx += 512) {
        int k = idx / NV, j = idx - k*NV;
        Msh[k*132 + j] = Cg[idx];
    }
    __syncthreads();
    // phase 5: Axi_k -> s_new, res, r-pack(s)
    if (t < 480) {
        int m = t / 60, kb = t - (t / 60) * 60;
        float4 a0 = {0,0,0,0}, a1 = {0,0,0,0}, a2 = {0,0,0,0}, a3 = {0,0,0,0};
        for (int jg = 0; jg < 30; ++jg) {
            float4 x4 = *(const float4*)&xl[m][jg*4];
            float4 c0 = *(const float4*)&Msh[(kb      ) * 132 + jg*4];
            float4 c1 = *(const float4*)&Msh[(kb + 60 ) * 132 + jg*4];
            float4 c2 = *(const float4*)&Msh[(kb + 120) * 132 + jg*4];
            float4 c3 = *(const float4*)&Msh[(kb + 180) * 132 + jg*4];
            a0.x += x4.x*c0.x; a0.y += x4.y*c0.y; a0.z += x4.z*c0.z; a0.w += x4.w*c0.w;
            a1.x += x4.x*c1.x; a1.y += x4.y*c1.y; a1.z += x4.z*c1.z; a1.w += x4.w*c1.w;
            a2.x += x4.x*c2.x; a2.y += x4.y*c2.y; a2.z += x4.z*c2.z; a2.w += x4.w*c2.w;
            a3.x += x4.x*c3.x; a3.y += x4.y*c3.y; a3.z += x4.z*c3.z; a3.w += x4.w*c3.w;
        }
        #pragma unroll
        for (int p = 0; p < 4; ++p) {
            int k = kb + 60*p;
            float a = (p == 0) ? hadd4(a0) : (p == 1) ? hadd4(a1) : (p == 2) ? hadd4(a2) : hadd4(a3);
            float sn = fmaxf(0.f, c[k] - a);
            float rv = a - c[k] + sn;
            resl[m][k] = rv;
            int b = b0 + m;
            snew[(size_t)b*NCN + k] = sn;
            float so = s[(size_t)b*NCN + k];
            size_t base = (size_t)b * KCAT;
            write2(act, base, k, so);
            write2(act, base, 360 + k, sn);
            write2(act, base, 720 + k, sn - so);
        }
    }
    __syncthreads();
    // restage CT + primal
    if (t < XB) {
        float a = 0.f;
        for (int k = 0; k < NCN; ++k) a += resl[t][k] * resl[t][k];
        primal[b0 + t] = sqrtf(a);
    }
    for (int idx = t; idx < NV*NCN; idx += 512) {
        int i = idx / NCN, k = idx - i*NCN;
        Msh[i*244 + k] = CTg[idx];
    }
    __syncthreads();
    // phase 6: lam update + r-pack(lam)
    if (t < 240) {
        int m = t / 30, ib = t - (t / 30) * 30;
        float4 a0 = {0,0,0,0}, a1 = {0,0,0,0}, a2 = {0,0,0,0}, a3 = {0,0,0,0};
        for (int kg = 0; kg < 60; ++kg) {
            float4 r4 = *(const float4*)&resl[m][kg*4];
            float4 c0 = *(const float4*)&Msh[(ib     ) * 244 + kg*4];
            float4 c1 = *(const float4*)&Msh[(ib + 30) * 244 + kg*4];
            float4 c2 = *(const float4*)&Msh[(ib + 60) * 244 + kg*4];
            float4 c3 = *(const float4*)&Msh[(ib + 90) * 244 + kg*4];
            a0.x += r4.x*c0.x; a0.y += r4.y*c0.y; a0.z += r4.z*c0.z; a0.w += r4.w*c0.w;
            a1.x += r4.x*c1.x; a1.y += r4.y*c1.y; a1.z += r4.z*c1.z; a1.w += r4.w*c1.w;
            a2.x += r4.x*c2.x; a2.y += r4.y*c2.y; a2.z += r4.z*c2.z; a2.w += r4.w*c2.w;
            a3.x += r4.x*c3.x; a3.y += r4.y*c3.y; a3.z += r4.z*c3.z; a3.w += r4.w*c3.w;
        }
        #pragma unroll
        for (int p = 0; p < 4; ++p) {
            int i = ib + 30*p;
            float a = (p == 0) ? hadd4(a0) : (p == 1) ? hadd4(a1) : (p == 2) ? hadd4(a2) : hadd4(a3);
            int b = b0 + m;
            float lo = lam[(size_t)b*NV + i];
            float ln = lo - a;
            lamn[(size_t)b*NV + i] = ln;
            size_t base = (size_t)b * KCAT;
            write2(act, base, 240 + i, lo);
            write2(act, base, 600 + i, ln);
            write2(act, base, 960 + i, ln - lo);
        }
    }
    for (int idx = t; idx < XB*8; idx += 512) {
        int m = idx >> 3, k = 1080 + (idx & 7);
        size_t base = (size_t)(b0 + m) * KCAT;
        act[base + k] = 0;
        act[base + 1088 + k] = 0;
    }
    // phase 7 (fused k_qp_part): Gram/v/S partials from xl (valid since ph3)
    for (int idx = t; idx < NV*NV; idx += 512) {
        int i = idx / NV, j = idx - i*NV;
        double a = 0.0;
        #pragma unroll
        for (int m = 0; m < XB; ++m) a += (double)xl[m][i] * (double)xl[m][j];
        Gp[(size_t)blockIdx.x*NV*NV + idx] = a;
    }
    if (t < NV) {
        double a = 0.0;
        #pragma unroll
        for (int m = 0; m < XB; ++m) a += (double)wl[m] * (double)xl[m][t];
        vp[(size_t)blockIdx.x*NV + t] = a;
    }
    if (t == 0) {
        double a = 0.0;
        #pragma unroll
        for (int m = 0; m < XB; ++m) a += (double)wl[m] * (double)wl[m];
        Sp[blockIdx.x] = a;
    }
}

__global__ void k_qp_red(const double* __restrict__ Gp, const double* __restrict__ vp,
                         const double* __restrict__ Sp,
                         double* __restrict__ G, double* __restrict__ v, double* __restrict__ S) {
    int idx = blockIdx.x * 256 + threadIdx.x;
    if (idx < NV*NV) {
        double a = 0.0;
        for (int p = 0; p < NPART; ++p) a += Gp[(size_t)p*NV*NV + idx];
        G[idx] = a;
    }
    if (idx < NV) {
        double a = 0.0;
        for (int p = 0; p < NPART; ++p) a += vp[(size_t)p*NV + idx];
        v[idx] = a;
    }
    if (idx == 0) {
        double a = 0.0;
        for (int p = 0; p < NPART; ++p) a += Sp[p];
        S[0] = a;
    }
}

// ---------------------------------------------------------------------------
// Merged tail: qp_norm (Yb + Gfin -> qp) AND fin (outb -> s/lam update + fx).
// Independent bodies, one dispatch. 16 batches/block, grid 256.
__global__ __launch_bounds__(256) void k_tail(
        const float* __restrict__ Yb, const double* __restrict__ G,
        const double* __restrict__ v, const double* __restrict__ S,
        float* __restrict__ qp,
        const float* __restrict__ snew, const float* __restrict__ lamn,
        const float* __restrict__ outb,
        float* __restrict__ s, float* __restrict__ lam,
        float* __restrict__ fx) {
    __shared__ float Yl[16][NV];
    __shared__ double tl[16][NV];
    __shared__ float redS[16][17];
    __shared__ float redL[16][17];
    int b0 = blockIdx.x * 16;
    int t = threadIdx.x;
    // ---- qp_norm ----
    for (int idx = t; idx < 16*NV; idx += 256) Yl[idx/NV][idx%NV] = Yb[(size_t)b0*NV + idx];
    __syncthreads();
    for (int idx = t; idx < 16*NV; idx += 256) {
        int m = idx / NV, i = idx % NV;
        double a = 0.0;
        for (int j = 0; j < NV; ++j) a += G[j*NV + i] * (double)Yl[m][j];  // G symmetric
        tl[m][i] = a;
    }
    __syncthreads();
    if (t < 16) {
        double a = 0.0, bv = 0.0;
        for (int i = 0; i < NV; ++i) { a += (double)Yl[t][i] * tl[t][i]; bv += (double)Yl[t][i] * v[i]; }
        double q = 0.25 * a + bv + S[0];
        qp[b0 + t] = (float)sqrt(q > 0.0 ? q : 0.0);
    }
    // ---- fin ----
    int tm = t / 16;
    int tk = t % 16;
    int b = b0 + tm;
    float ds2 = 0.f, dl2 = 0.f;
    for (int k = tk; k < NCN; k += 16) {
        float o = outb[(size_t)b*NOUTP + k];
        float sf = fmaxf(0.f, snew[(size_t)b*NCN + k] + o);
        float so = s[(size_t)b*NCN + k];
        s[(size_t)b*NCN + k] = sf;
        float d = so - sf;
        ds2 += d * d;
    }
    for (int i = tk; i < NV; i += 16) {
        float o = outb[(size_t)b*NOUTP + NCN + i];
        float lf = lamn[(size_t)b*NV + i] + o;
        float lo = lam[(size_t)b*NV + i];
        lam[(size_t)b*NV + i] = lf;
        float d = lo - lf;
        dl2 += d * d;
    }
    redS[tm][tk] = ds2;
    redL[tm][tk] = dl2;
    __syncthreads();
    if (tk == 0) {
        float a = 0.f, l = 0.f;
        for (int q = 0; q < 16; ++q) { a += redS[tm][q]; l += redL[tm][q]; }
        fx[b] = sqrtf(l) + sqrtf(a);
    }
}

// ---------------------------------------------------------------------------
// Fused GRU cell, bf16 x bf16 (a_hi only): tile 64 x 128 x 3 gates, 512 thr
// (8 waves = 2m x 4n), 2-buffer LDS 64KB/block -> 2 blocks/CU. 12 MFMA +
// 8 ds_read_b128 per wave per step. XCD m-ownership. Epilogue reconstructs
// hv from stored h_hi+h_lo (state carry stays near-f32).
#define GRUF_STEP(NSLOT, BUFI) do {                                              \
    char* Ah_ = lds + (BUFI) * 32768;                                            \
    char* Bb_ = Ah_ + 8192;                                                      \
    const int srow = lane & 15;                                                  \
    const int ksl = lane >> 4;                                                   \
    short8v ah[2];                                                               \
    _Pragma("unroll")                                                            \
    for (int fm = 0; fm < 2; ++fm) {                                             \
        int rr = wm * 32 + fm * 16 + srow;                                       \
        int off = rr * 64 + ((ksl ^ ((rr >> 1) & 3)) << 4);                      \
        ah[fm] = *(const short8v*)(Ah_ + off);                                   \
    }                                                                            \
    _Pragma("unroll")                                                            \
    for (int fn = 0; fn < 2; ++fn) {                                             \
        int rb = wn * 32 + fn * 16 + srow;                                       \
        int boff = rb * 64 + ((ksl ^ ((rb >> 1) & 3)) << 4);                     \
        short8v bfr = *(const short8v*)(Bb_ + boff);                             \
        short8v bfz = *(const short8v*)(Bb_ + 8192 + boff);                      \
        short8v bfn = *(const short8v*)(Bb_ + 16384 + boff);                     \
        _Pragma("unroll")                                                        \
        for (int fm = 0; fm < 2; ++fm) {                                         \
            acc[0][fn][fm] = __builtin_amdgcn_mfma_f32_16x16x32_bf16(ah[fm], bfr, acc[0][fn][fm], 0, 0, 0); \
            acc[1][fn][fm] = __builtin_amdgcn_mfma_f32_16x16x32_bf16(ah[fm], bfz, acc[1][fn][fm], 0, 0, 0); \
            acc[NSLOT][fn][fm] = __builtin_amdgcn_mfma_f32_16x16x32_bf16(ah[fm], bfn, acc[NSLOT][fn][fm], 0, 0, 0); \
        }                                                                        \
    }                                                                            \
} while (0)

__global__ __launch_bounds__(512) void k_gruf(
        const u16* __restrict__ act,   // [NB][KCAT]: r filled + h_cur
        const u16* __restrict__ Wc,    // [3*1024][KWC]
        const float* __restrict__ bih, const float* __restrict__ bhh,
        u16* __restrict__ actn) {      // h_new -> h-section
    __shared__ char lds[65536];        // 2 x (A_hi 4K + pad 4K + B 24K)
    const int t = threadIdx.x;
    const int lane = t & 63;
    const int wid = t >> 6;          // 0..7
    const int wm = wid >> 2;         // 0..1: 32-row band
    const int wn = wid & 3;          // 0..3: 32-col band per gate
    const int bid = blockIdx.x;
    const int xcd = bid & 7;
    const int slot = bid >> 3;       // 0..63
    const int m0 = (xcd * 8 + (slot & 7)) * 64;
    const int n0 = (slot >> 3) * 128;

    f32x4 acc[4][2][2];
    #pragma unroll
    for (int i = 0; i < 4; ++i)
        #pragma unroll
        for (int j = 0; j < 2; ++j)
            #pragma unroll
            for (int k = 0; k < 2; ++k) {
                f32x4 z = {0.f, 0.f, 0.f, 0.f};
                acc[i][j][k] = z;
            }

    auto stage = [&](int step, int buf) {   // waves 0-3: 1 A + 3 B; waves 4-7: 3 B
        char* Ah_ = lds + buf * 32768;
        char* Bb_ = Ah_ + 8192;
        const int hiOff = (step < NSTEP_R) ? step * 32 : step * 32 + 1088;
        const int wOff = step * 32;
        if (wid < 4) {
            int rr = (wid & 3) * 16 + (lane >> 2);     // 0..63
            int kq = ((lane & 3) ^ ((rr >> 1) & 3)) << 3;
            gl16(act + (size_t)(m0 + rr) * KCAT + hiOff + kq, Ah_ + (wid & 3) * 1024);
        }
        #pragma unroll
        for (int j = 0; j < 3; ++j) {
            int cb = wid * 3 + j;              // 0..23
            int rbg = cb * 16 + (lane >> 2);   // 0..383
            int kq = ((lane & 3) ^ ((rbg >> 1) & 3)) << 3;
            gl16(Wc + (size_t)((rbg >> 7) * 1024 + n0 + (rbg & 127)) * KWC + wOff + kq,
                 Bb_ + cb * 1024);
        }
    };

    stage(0, 0);
    __syncthreads();
    int cur = 0;
    for (int step = 0; step < NSTEP_R; ++step) {       // r-part: n-gate -> i_n
        stage(step + 1, cur ^ 1);
        GRUF_STEP(2, cur);
        __syncthreads();
        cur ^= 1;
    }
    for (int step = NSTEP_R; step < NSTEPS; ++step) {  // h-part: n-gate -> h_n
        if (step + 1 < NSTEPS) stage(step + 1, cur ^ 1);
        GRUF_STEP(3, cur);
        __syncthreads();
        cur ^= 1;
    }

    #pragma unroll
    for (int fn = 0; fn < 2; ++fn) {
        const int jj = n0 + wn * 32 + fn * 16 + (lane & 15);
        const float bir = bih[jj],        bhr = bhh[jj];
        const float biz = bih[1024 + jj], bhz = bhh[1024 + jj];
        const float bin = bih[2048 + jj], bhn = bhh[2048 + jj];
        #pragma unroll
        for (int fm = 0; fm < 2; ++fm) {
            #pragma unroll
            for (int rg = 0; rg < 4; ++rg) {
                int m = m0 + wm * 32 + fm * 16 + (lane >> 4) * 4 + rg;
                float rz = acc[0][fn][fm][rg];
                float zz = acc[1][fn][fm][rg];
                float inn = acc[2][fn][fm][rg];
                float hnn = acc[3][fn][fm][rg];
                float rgate = 1.f / (1.f + expf(-(rz + bir + bhr)));
                float zgate = 1.f / (1.f + expf(-(zz + biz + bhz)));
                float ngate = tanhf(inn + bin + rgate * (hnn + bhn));
                size_t base = (size_t)m * KCAT + HOFF;
                float hv = b2f(act[base + jj]) + b2f(act[base + HIDD + jj]);
                float hnew = (1.f - zgate) * ngate + zgate * hv;
                u16 nh = f2b(hnew);
                actn[base + jj] = nh;
                actn[base + HIDD + jj] = f2b(hnew - b2f(nh));
            }
        }
    }
}

// out = h_hi @ W_out^T + b_out; tile 64 x 128, grid (64,3), 2-buf 32KB.
__global__ __launch_bounds__(512) void k_outp(
        const u16* __restrict__ act, const u16* __restrict__ Wo,
        const float* __restrict__ bo, float* __restrict__ outb) {
    __shared__ char lds[32768];        // 2 x (A_hi 4K + pad 4K + B 8K)
    const int t = threadIdx.x;
    const int lane = t & 63;
    const int wid = t >> 6;
    const int wm = wid >> 2;           // 0..1
    const int wn = wid & 3;            // 0..3
    const int m0 = blockIdx.x * 64;
    const int n0 = blockIdx.y * 128;
    f32x4 acc[2][2];
    #pragma unroll
    for (int i = 0; i < 2; ++i)
        #pragma unroll
        for (int j = 0; j < 2; ++j) {
            f32x4 z = {0.f, 0.f, 0.f, 0.f};
            acc[i][j] = z;
        }

    auto stage = [&](int step, int buf) {
        char* Ah_ = lds + buf * 16384;
        char* Bb_ = Ah_ + 8192;
        if (wid < 4) {
            int rr = (wid & 3) * 16 + (lane >> 2);     // 0..63
            int kq = ((lane & 3) ^ ((rr >> 1) & 3)) << 3;
            gl16(act + (size_t)(m0 + rr) * KCAT + HOFF + step * 32 + kq,
                 Ah_ + (wid & 3) * 1024);
        }
        {
            int rb = wid * 16 + (lane >> 2);           // 0..127
            int kq = ((lane & 3) ^ ((rb >> 1) & 3)) << 3;
            gl16(Wo + (size_t)(n0 + rb) * KWO + step * 32 + kq, Bb_ + wid * 1024);
        }
    };

    stage(0, 0);
    __syncthreads();
    int cur = 0;
    for (int step = 0; step < 32; ++step) {
        if (step + 1 < 32) stage(step + 1, cur ^ 1);
        {
            char* Ah_ = lds + cur * 16384;
            char* Bb_ = Ah_ + 8192;
            const int srow = lane & 15;
            const int ksl = lane >> 4;
            short8v ah[2];
            #pragma unroll
            for (int fm = 0; fm < 2; ++fm) {
                int rr = wm * 32 + fm * 16 + srow;
                int off = rr * 64 + ((ksl ^ ((rr >> 1) & 3)) << 4);
                ah[fm] = *(const short8v*)(Ah_ + off);
            }
            #pragma unroll
            for (int fn = 0; fn < 2; ++fn) {
                int rb = wn * 32 + fn * 16 + srow;
                int boff = rb * 64 + ((ksl ^ ((rb >> 1) & 3)) << 4);
                short8v bf = *(const short8v*)(Bb_ + boff);
                #pragma unroll
                for (int fm = 0; fm < 2; ++fm)
                    acc[fn][fm] = __builtin_amdgcn_mfma_f32_16x16x32_bf16(ah[fm], bf, acc[fn][fm], 0, 0, 0);
            }
        }
        __syncthreads();
        cur ^= 1;
    }
    #pragma unroll
    for (int fn = 0; fn < 2; ++fn) {
        int n = n0 + wn * 32 + fn * 16 + (lane & 15);
        if (n < NOUTD) {
            float bb = bo[n];
            #pragma unroll
            for (int fm = 0; fm < 2; ++fm) {
                #pragma unroll
                for (int rg = 0; rg < 4; ++rg) {
                    int m = m0 + wm * 32 + fm * 16 + (lane >> 4) * 4 + rg;
                    outb[(size_t)m * NOUTP + n] = acc[fn][fm][rg] + bb;
                }
            }
        }
    }
}

// ---------------------------------------------------------------------------
extern "C" void kernel_launch(void* const* d_in, const int* in_sizes, int n_in,
                              void* d_out, int out_size, void* d_ws, size_t ws_size,
                              hipStream_t stream) {
    const float* lamda_init = (const float*)d_in[0];
    // d_in[1] = s_init (unused: multiplied by 0 in reference)
    const float* h0    = (const float*)d_in[2];
    const float* H     = (const float*)d_in[3];
    const float* g     = (const float*)d_in[4];
    const float* C     = (const float*)d_in[5];
    const float* c     = (const float*)d_in[6];
    const float* W_ih  = (const float*)d_in[7];
    const float* b_ih  = (const float*)d_in[8];
    const float* W_hh  = (const float*)d_in[9];
    const float* b_hh  = (const float*)d_in[10];
    const float* W_out = (const float*)d_in[11];
    const float* b_out = (const float*)d_in[12];

    float* out    = (float*)d_out;
    float* xi_out = out;                       // [B,120]
    float* primal = out + (size_t)NB*NV;       // [8,B]
    float* fixedo = primal + (size_t)NITER*NB; // [8,B]
    float* qpres  = fixedo + (size_t)NITER*NB; // [8,B]

    char* wp = (char*)d_ws;
    auto alloc = [&](size_t bytes) {
        void* p = (void*)wp;
        wp += (bytes + 255) & ~(size_t)255;
        return p;
    };
    float* Amat  = (float*)alloc(NV*NV*4);
    float* A0m   = (float*)alloc(NV*NV*4);
    float* Qinv  = (float*)alloc(NV*NV*4);
    float* Qinv0 = (float*)alloc(NV*NV*4);
    float* CTg   = (float*)alloc((size_t)NV*NCN*4);
    float* s0v   = (float*)alloc(NCN*4);
    float* sbuf  = (float*)alloc((size_t)NB*NCN*4);
    float* snew  = (float*)alloc((size_t)NB*NCN*4);
    float* lam   = (float*)alloc((size_t)NB*NV*4);
    float* lamn  = (float*)alloc((size_t)NB*NV*4);
    float* xib   = (float*)alloc((size_t)NB*NV*4);
    float* Yb    = (float*)alloc((size_t)NB*NV*4);
    float* outb  = (float*)alloc((size_t)NB*NOUTP*4);
    u16* actA    = (u16*)alloc((size_t)NB*KCAT*2);
    u16* actB    = (u16*)alloc((size_t)NB*KCAT*2);
    u16* Wcat    = (u16*)alloc((size_t)3072*KWC*2);
    u16* Wopk    = (u16*)alloc((size_t)NOUTP*KWO*2);
    double* Gpart = (double*)alloc((size_t)NPART*NV*NV*8);
    double* vpart = (double*)alloc((size_t)NPART*NV*8);
    double* Spart = (double*)alloc(NPART*8);
    double* Gfin  = (double*)alloc(NV*NV*8);
    double* vfin  = (double*)alloc(NV*8);
    double* Sfin  = (double*)alloc(8);

    k_buildA<<<dim3(NV, 2), dim3(128), 0, stream>>>(H, C, Amat, A0m);
    k_buildCT<<<dim3(NV), dim3(256), 0, stream>>>(C, CTg);
    k_invert<<<dim3(2), dim3(1024), 0, stream>>>(Amat, A0m, Qinv, Qinv0);
    k_s0<<<dim3(1), dim3(256), 0, stream>>>(Qinv0, g, C, c, s0v);
    k_init<<<dim3(NB/8), dim3(256), 0, stream>>>(s0v, lamda_init, sbuf, lam);
    k_packWcat<<<dim3(3072), dim3(256), 0, stream>>>(W_ih, W_hh, Wcat);
    k_packWo<<<dim3(NOUTP), dim3(256), 0, stream>>>(W_out, Wopk);
    k_packH<<<dim3(NB), dim3(256), 0, stream>>>(h0, actA);

    u16* hc = actA;
    u16* hn2 = actB;
    for (int it = 0; it < NITER; ++it) {
        k_xiproj<<<dim3(NB/XB), dim3(512), 0, stream>>>(sbuf, lam, C, CTg, c, g, Qinv, H,
                                                        xib, Yb, snew, lamn, hc,
                                                        primal + (size_t)it*NB,
                                                        Gpart, vpart, Spart);
        k_qp_red<<<dim3((NV*NV + 255)/256), dim3(256), 0, stream>>>(Gpart, vpart, Spart, Gfin, vfin, Sfin);
        k_gruf<<<dim3(512), dim3(512), 0, stream>>>(hc, Wcat, b_ih, b_hh, hn2);
        k_outp<<<dim3(64, 3), dim3(512), 0, stream>>>(hn2, Wopk, b_out, outb);
        k_tail<<<dim3(NB/16), dim3(256), 0, stream>>>(Yb, Gfin, vfin, Sfin,
                                                      qpres + (size_t)it*NB,
                                                      snew, lamn, outb, sbuf, lam,
                                                      fixedo + (size_t)it*NB);
        u16* tmp = hc; hc = hn2; hn2 = tmp;
    }
    hipMemcpyAsync(xi_out, xib, (size_t)NB*NV*sizeof(float), hipMemcpyDeviceToDevice, stream);
}

// Round 15
// 2313.088 us; speedup vs baseline: 1.0353x; 1.0353x over previous
//
#include <hip/hip_runtime.h>
#include <hip/hip_bf16.h>
#include <math.h>

// Problem constants (match reference)
#define NB    4096   // num_batch
#define NV    120    // NVAR
#define NCN   240    // num constraints
#define HIDD  1024   // GRU hidden
#define RINN  1080   // GRU input dim
#define NOUTD 360    // NC+NVAR
#define NOUTP 384    // padded out cols
#define NITER 8
#define REGEPS 1e-4f
#define NPART 512    // Gram partials emitted by k_xiproj (one per block)

// 2-term split: activations [hi|lo] (exact), weights stored ONCE (hi).
// GEMMs consume BOTH a_hi and a_lo (round-14 ablation: dropping a_lo halves
// MFMA but exposes the staging critical path -> 113->142us REGRESSION).
// act row: [r_hi 1088 | r_lo 1088 | h_hi 1024 | h_lo 1024] = 4224
// Wcat row: [Wih_hi 1088 | Whh_hi 1024] = 2112 (B-reuse pairing)
#define KCAT 4224
#define HOFF 2176    // h section start within an act row
#define KWC  2112    // Wcat K
#define KWO  1024    // W_out packed K
#define NSTEP_R 34   // r-section 32-wide K-steps (1088/32)
#define NSTEPS  66   // total (2112/32)

typedef unsigned short u16;
typedef __attribute__((ext_vector_type(8))) short short8v;
typedef __attribute__((ext_vector_type(4))) float f32x4;

__device__ inline u16 f2b(float x) {
    __hip_bfloat16 h = __float2bfloat16(x);
    return __builtin_bit_cast(u16, h);
}
__device__ inline float b2f(u16 u) {
    __hip_bfloat16 h = __builtin_bit_cast(__hip_bfloat16, u);
    return __bfloat162float(h);
}

// async global -> LDS, 16B per lane (wave-uniform LDS base + lane*16)
__device__ inline void gl16(const void* g, void* l) {
    __builtin_amdgcn_global_load_lds(
        (__attribute__((address_space(1))) void*)(void*)g,
        (__attribute__((address_space(3))) void*)l, 16, 0, 0);
}

// ---------------------------------------------------------------------------
// Build A = H + C^T C + REG*I (which==0) and A0 = H + REG*I (which==1)
__global__ void k_buildA(const float* __restrict__ H, const float* __restrict__ C,
                         float* __restrict__ A, float* __restrict__ A0) {
    int i = blockIdx.x;
    int which = blockIdx.y;
    for (int j = threadIdx.x; j < NV; j += blockDim.x) {
        float v = H[i*NV + j] + (i == j ? REGEPS : 0.f);
        if (which == 0) {
            float acc = 0.f;
            for (int k = 0; k < NCN; ++k) acc += C[k*NV + i] * C[k*NV + j];
            A[i*NV + j] = v + acc;   // RHO = 1
        } else {
            A0[i*NV + j] = v;
        }
    }
}

// CT[j][k] = C[k][j]
__global__ void k_buildCT(const float* __restrict__ C, float* __restrict__ CT) {
    int j = blockIdx.x;   // 0..119
    for (int k = threadIdx.x; k < NCN; k += 256)
        CT[(size_t)j * NCN + k] = C[(size_t)k * NV + j];
}

// Row-major 4x4 inverse via 2x2-subdeterminant adjugate (ILP-friendly).
__device__ inline void inv4x4(const float* m, float* inv) {
    float s0 = m[0]*m[5] - m[1]*m[4];
    float s1 = m[0]*m[6] - m[2]*m[4];
    float s2 = m[0]*m[7] - m[3]*m[4];
    float s3 = m[1]*m[6] - m[2]*m[5];
    float s4 = m[1]*m[7] - m[3]*m[5];
    float s5 = m[2]*m[7] - m[3]*m[6];
    float c5 = m[10]*m[15] - m[11]*m[14];
    float c4 = m[9]*m[15] - m[11]*m[13];
    float c3 = m[9]*m[14] - m[10]*m[13];
    float c2 = m[8]*m[15] - m[11]*m[12];
    float c1 = m[8]*m[14] - m[10]*m[12];
    float c0 = m[8]*m[13] - m[9]*m[12];
    float det = s0*c5 - s1*c4 + s2*c3 + s3*c2 - s4*c1 + s5*c0;
    float id = 1.0f / det;
    inv[0]  = ( m[5]*c5 - m[6]*c4 + m[7]*c3) * id;
    inv[1]  = (-m[1]*c5 + m[2]*c4 - m[3]*c3) * id;
    inv[2]  = ( m[13]*s5 - m[14]*s4 + m[15]*s3) * id;
    inv[3]  = (-m[9]*s5 + m[10]*s4 - m[11]*s3) * id;
    inv[4]  = (-m[4]*c5 + m[6]*c2 - m[7]*c1) * id;
    inv[5]  = ( m[0]*c5 - m[2]*c2 + m[3]*c1) * id;
    inv[6]  = (-m[12]*s5 + m[14]*s2 - m[15]*s1) * id;
    inv[7]  = ( m[8]*s5 - m[10]*s2 + m[11]*s1) * id;
    inv[8]  = ( m[4]*c4 - m[5]*c2 + m[7]*c0) * id;
    inv[9]  = (-m[0]*c4 + m[1]*c2 - m[3]*c0) * id;
    inv[10] = ( m[12]*s4 - m[13]*s2 + m[15]*s0) * id;
    inv[11] = (-m[8]*s4 + m[9]*s2 - m[11]*s0) * id;
    inv[12] = (-m[4]*c3 + m[5]*c1 - m[6]*c0) * id;
    inv[13] = ( m[0]*c3 - m[1]*c1 + m[2]*c0) * id;
    inv[14] = (-m[12]*s3 + m[13]*s1 - m[14]*s0) * id;
    inv[15] = ( m[8]*s3 - m[9]*s1 + m[10]*s0) * id;
}

// Blocked rank-4 Gauss-Jordan, phase-split. 2 barriers/chunk, 30 chunks.
__global__ __launch_bounds__(1024) void k_invert(const float* __restrict__ Ain,
                                                 const float* __restrict__ A0in,
                                                 float* __restrict__ Qi,
                                                 float* __restrict__ Qi0) {
    __shared__ float M[NV][132];
    __shared__ float Rl[4][132];
    __shared__ float Bl[16];
    const float* src = (blockIdx.x == 0) ? Ain : A0in;
    float* dst = (blockIdx.x == 0) ? Qi : Qi0;
    const int t = threadIdx.x;
    for (int idx = t; idx < NV*132; idx += 1024) {
        int i = idx / 132, j = idx - i*132;
        M[i][j] = (j < NV) ? src[i*NV + j] : 0.f;
    }
    __syncthreads();
    const int ty = t >> 5;        // 0..31 row owner (4 rows each)
    const int g4 = (t & 31) * 4;  // col group 0..124
    for (int kk = 0; kk < NV; kk += 4) {
        if (ty == 0) {
            float a[16], b[16];
            #pragma unroll
            for (int p = 0; p < 4; ++p) {
                float4 v = *(const float4*)&M[kk + p][kk];
                a[p*4+0] = v.x; a[p*4+1] = v.y; a[p*4+2] = v.z; a[p*4+3] = v.w;
            }
            inv4x4(a, b);
            float4 m0v = *(const float4*)&M[kk+0][g4];
            float4 m1v = *(const float4*)&M[kk+1][g4];
            float4 m2v = *(const float4*)&M[kk+2][g4];
            float4 m3v = *(const float4*)&M[kk+3][g4];
            #pragma unroll
            for (int p = 0; p < 4; ++p) {
                float4 r;
                r.x = b[p*4+0]*m0v.x + b[p*4+1]*m1v.x + b[p*4+2]*m2v.x + b[p*4+3]*m3v.x;
                r.y = b[p*4+0]*m0v.y + b[p*4+1]*m1v.y + b[p*4+2]*m2v.y + b[p*4+3]*m3v.y;
                r.z = b[p*4+0]*m0v.z + b[p*4+1]*m1v.z + b[p*4+2]*m2v.z + b[p*4+3]*m3v.z;
                r.w = b[p*4+0]*m0v.w + b[p*4+1]*m1v.w + b[p*4+2]*m2v.w + b[p*4+3]*m3v.w;
                *(float4*)&Rl[p][g4] = r;
            }
            if (t < 16) Bl[t] = b[t];
        }
        float4 F[4];
        #pragma unroll
        for (int q = 0; q < 4; ++q) {
            int i = ty + 32*q;
            F[q] = (i < NV) ? *(const float4*)&M[i][kk] : float4{0.f,0.f,0.f,0.f};
        }
        __syncthreads();
        #pragma unroll
        for (int q = 0; q < 4; ++q) {
            int i = ty + 32*q;
            if (i < NV) {
                int dp = i - kk;
                bool ispiv = (dp >= 0) && (dp < 4);
                float4 v;
                if (g4 == kk) {
                    if (ispiv) {
                        v = *(const float4*)&Bl[dp*4];
                    } else {
                        v.x = -(F[q].x*Bl[0] + F[q].y*Bl[4] + F[q].z*Bl[8]  + F[q].w*Bl[12]);
                        v.y = -(F[q].x*Bl[1] + F[q].y*Bl[5] + F[q].z*Bl[9]  + F[q].w*Bl[13]);
                        v.z = -(F[q].x*Bl[2] + F[q].y*Bl[6] + F[q].z*Bl[10] + F[q].w*Bl[14]);
                        v.w = -(F[q].x*Bl[3] + F[q].y*Bl[7] + F[q].z*Bl[11] + F[q].w*Bl[15]);
                    }
                } else if (ispiv) {
                    v = *(const float4*)&Rl[dp][g4];
                } else {
                    float4 r0 = *(const float4*)&Rl[0][g4];
                    float4 r1 = *(const float4*)&Rl[1][g4];
                    float4 r2 = *(const float4*)&Rl[2][g4];
                    float4 r3 = *(const float4*)&Rl[3][g4];
                    v = *(const float4*)&M[i][g4];
                    v.x -= F[q].x*r0.x + F[q].y*r1.x + F[q].z*r2.x + F[q].w*r3.x;
                    v.y -= F[q].x*r0.y + F[q].y*r1.y + F[q].z*r2.y + F[q].w*r3.y;
                    v.z -= F[q].x*r0.z + F[q].y*r1.z + F[q].z*r2.z + F[q].w*r3.z;
                    v.w -= F[q].x*r0.w + F[q].y*r1.w + F[q].z*r2.w + F[q].w*r3.w;
                }
                *(float4*)&M[i][g4] = v;
            }
        }
        __syncthreads();
    }
    for (int idx = t; idx < NV*NV; idx += 1024) {
        int i = idx / NV, j = idx - i*NV;
        dst[idx] = M[i][j];
    }
}

// xi0 = (-g) @ Qinv0^T ; s0 = max(0, c - C xi0)   (batch-constant vectors)
__global__ void k_s0(const float* __restrict__ Qi0, const float* __restrict__ g,
                     const float* __restrict__ C, const float* __restrict__ c,
                     float* __restrict__ s0v) {
    __shared__ float xi0[NV];
    int t = threadIdx.x;
    if (t < NV) {
        float a = 0.f;
        for (int j = 0; j < NV; ++j) a += Qi0[t*NV + j] * g[j];
        xi0[t] = -a;
    }
    __syncthreads();
    if (t < NCN) {
        float a = 0.f;
        for (int j = 0; j < NV; ++j) a += C[t*NV + j] * xi0[j];
        s0v[t] = fmaxf(0.f, c[t] - a);
    }
}

// Initialize state: s = broadcast(s0), lam = lamda_init
__global__ void k_init(const float* __restrict__ s0v, const float* __restrict__ lam0,
                       float* __restrict__ s, float* __restrict__ lam) {
    int b0 = blockIdx.x * 8;
    int t = threadIdx.x;
    for (int idx = t; idx < 8*NCN; idx += 256) {
        int m = idx / NCN, k = idx % NCN;
        s[(size_t)(b0 + m)*NCN + k] = s0v[k];
    }
    for (int idx = t; idx < 8*NV; idx += 256) lam[(size_t)b0*NV + idx] = lam0[(size_t)b0*NV + idx];
}

// Pack h0 into act buffer h-section: [h_hi | h_lo]
__global__ void k_packH(const float* __restrict__ h0, u16* __restrict__ act) {
    int n = blockIdx.x;
    size_t base = (size_t)n * KCAT + HOFF;
    for (int k = threadIdx.x; k < HIDD; k += 256) {
        float x = h0[(size_t)n * HIDD + k];
        u16 hi = f2b(x);
        act[base + k] = hi;
        act[base + HIDD + k] = f2b(x - b2f(hi));
    }
}

// Pack Wih+Whh (hi only, once): [Wih_hi 1088 | Whh_hi 1024]
__global__ void k_packWcat(const float* __restrict__ Wih, const float* __restrict__ Whh,
                           u16* __restrict__ Wc) {
    int n = blockIdx.x;   // 0..3071
    size_t base = (size_t)n * KWC;
    for (int k = threadIdx.x; k < 1088; k += 256)
        Wc[base + k] = f2b(k < RINN ? Wih[(size_t)n * RINN + k] : 0.f);
    for (int k = threadIdx.x; k < HIDD; k += 256)
        Wc[base + 1088 + k] = f2b(Whh[(size_t)n * HIDD + k]);
}

// Pack W_out (hi only): [NOUTP rows][1024]
__global__ void k_packWo(const float* __restrict__ src, u16* __restrict__ dst) {
    int n = blockIdx.x;
    size_t row = (size_t)n * KWO;
    for (int k = threadIdx.x; k < KWO; k += 256)
        dst[row + k] = f2b(n < NOUTD ? src[(size_t)n * HIDD + k] : 0.f);
}

__device__ inline void write2(u16* __restrict__ act, size_t base, int pos, float x) {
    u16 hi = f2b(x);
    u16 lo = f2b(x - b2f(hi));
    act[base + pos] = hi;
    act[base + 1088 + pos] = lo;
}

__device__ inline float hadd4(float4 v) { return (v.x + v.y) + (v.z + v.w); }

// ---------------------------------------------------------------------------
// Fused: xi solve + projection + GRU-input pack + Gram/v/S partials.
// 8 batches/block, 512 blocks. float4 LDS, strides 132/244.
#define XB 8
__global__ __launch_bounds__(512) void k_xiproj(
        const float* __restrict__ s, const float* __restrict__ lam,
        const float* __restrict__ Cg, const float* __restrict__ CTg,
        const float* __restrict__ c,
        const float* __restrict__ g, const float* __restrict__ Qi,
        const float* __restrict__ Hg,
        float* __restrict__ xi, float* __restrict__ Y,
        float* __restrict__ snew, float* __restrict__ lamn,
        u16* __restrict__ act, float* __restrict__ primal,
        double* __restrict__ Gp, double* __restrict__ vp, double* __restrict__ Sp) {
    __shared__ float Msh[31680];      // C/QH: [240][132]; CT: [120][244]
    __shared__ float bd[XB][NCN];
    __shared__ float ul[XB][NV];
    __shared__ float xl[XB][NV];
    __shared__ float resl[XB][NCN];
    __shared__ float wl[XB];
    const int b0 = blockIdx.x * XB;
    const int t = threadIdx.x;

    for (int idx = t; idx < XB*NCN; idx += 512) {
        int m = idx / NCN, k = idx - m*NCN;
        bd[m][k] = c[k] - s[(size_t)(b0 + m)*NCN + k];
    }
    for (int idx = t; idx < NV*NCN; idx += 512) {
        int i = idx / NCN, k = idx - i*NCN;
        Msh[i*244 + k] = CTg[idx];
    }
    __syncthreads();
    if (t < 240) {
        int m = t / 30, jb = t - (t / 30) * 30;
        float4 a0 = {0,0,0,0}, a1 = {0,0,0,0}, a2 = {0,0,0,0}, a3 = {0,0,0,0};
        for (int kg = 0; kg < 60; ++kg) {
            float4 b4 = *(const float4*)&bd[m][kg*4];
            float4 c0 = *(const float4*)&Msh[(jb     ) * 244 + kg*4];
            float4 c1 = *(const float4*)&Msh[(jb + 30) * 244 + kg*4];
            float4 c2 = *(const float4*)&Msh[(jb + 60) * 244 + kg*4];
            float4 c3 = *(const float4*)&Msh[(jb + 90) * 244 + kg*4];
            a0.x += b4.x*c0.x; a0.y += b4.y*c0.y; a0.z += b4.z*c0.z; a0.w += b4.w*c0.w;
            a1.x += b4.x*c1.x; a1.y += b4.y*c1.y; a1.z += b4.z*c1.z; a1.w += b4.w*c1.w;
            a2.x += b4.x*c2.x; a2.y += b4.y*c2.y; a2.z += b4.z*c2.z; a2.w += b4.w*c2.w;
            a3.x += b4.x*c3.x; a3.y += b4.y*c3.y; a3.z += b4.z*c3.z; a3.w += b4.w*c3.w;
        }
        #pragma unroll
        for (int p = 0; p < 4; ++p) {
            int j = jb + 30*p;
            float h = (p == 0) ? hadd4(a0) : (p == 1) ? hadd4(a1) : (p == 2) ? hadd4(a2) : hadd4(a3);
            ul[m][j] = lam[(size_t)(b0 + m)*NV + j] - g[j] + h;
        }
    }
    __syncthreads();
    for (int idx = t; idx < NV*NV; idx += 512) {
        int i = idx / NV, j = idx - i*NV;
        Msh[i*132 + j] = Qi[idx];
        Msh[(120 + i)*132 + j] = Hg[idx];
    }
    __syncthreads();
    if (t < 240) {
        int m = t / 30, ib = t - (t / 30) * 30;
        float4 a0 = {0,0,0,0}, a1 = {0,0,0,0}, a2 = {0,0,0,0}, a3 = {0,0,0,0};
        for (int jg = 0; jg < 30; ++jg) {
            float4 u4 = *(const float4*)&ul[m][jg*4];
            float4 q0 = *(const float4*)&Msh[(ib     ) * 132 + jg*4];
            float4 q1 = *(const float4*)&Msh[(ib + 30) * 132 + jg*4];
            float4 q2 = *(const float4*)&Msh[(ib + 60) * 132 + jg*4];
            float4 q3 = *(const float4*)&Msh[(ib + 90) * 132 + jg*4];
            a0.x += u4.x*q0.x; a0.y += u4.y*q0.y; a0.z += u4.z*q0.z; a0.w += u4.w*q0.w;
            a1.x += u4.x*q1.x; a1.y += u4.y*q1.y; a1.z += u4.z*q1.z; a1.w += u4.w*q1.w;
            a2.x += u4.x*q2.x; a2.y += u4.y*q2.y; a2.z += u4.z*q2.z; a2.w += u4.w*q2.w;
            a3.x += u4.x*q3.x; a3.y += u4.y*q3.y; a3.z += u4.z*q3.z; a3.w += u4.w*q3.w;
        }
        #pragma unroll
        for (int p = 0; p < 4; ++p) {
            int i = ib + 30*p;
            float a = (p == 0) ? hadd4(a0) : (p == 1) ? hadd4(a1) : (p == 2) ? hadd4(a2) : hadd4(a3);
            xl[m][i] = a;
            xi[(size_t)(b0 + m)*NV + i] = a;
        }
    }
    __syncthreads();
    if (t < 240) {
        int m = t / 30, ib = t - (t / 30) * 30;
        float4 a0 = {0,0,0,0}, a1 = {0,0,0,0}, a2 = {0,0,0,0}, a3 = {0,0,0,0};
        for (int jg = 0; jg < 30; ++jg) {
            float4 x4 = *(const float4*)&xl[m][jg*4];
            float4 h0 = *(const float4*)&Msh[(120 + ib     ) * 132 + jg*4];
            float4 h1 = *(const float4*)&Msh[(120 + ib + 30) * 132 + jg*4];
            float4 h2 = *(const float4*)&Msh[(120 + ib + 60) * 132 + jg*4];
            float4 h3 = *(const float4*)&Msh[(120 + ib + 90) * 132 + jg*4];
            a0.x += x4.x*h0.x; a0.y += x4.y*h0.y; a0.z += x4.z*h0.z; a0.w += x4.w*h0.w;
            a1.x += x4.x*h1.x; a1.y += x4.y*h1.y; a1.z += x4.z*h1.z; a1.w += x4.w*h1.w;
            a2.x += x4.x*h2.x; a2.y += x4.y*h2.y; a2.z += x4.z*h2.z; a2.w += x4.w*h2.w;
            a3.x += x4.x*h3.x; a3.y += x4.y*h3.y; a3.z += x4.z*h3.z; a3.w += x4.w*h3.w;
        }
        #pragma unroll
        for (int p = 0; p < 4; ++p) {
            int i = ib + 30*p;
            float a = (p == 0) ? hadd4(a0) : (p == 1) ? hadd4(a1) : (p == 2) ? hadd4(a2) : hadd4(a3);
            Y[(size_t)(b0 + m)*NV + i] = a;
        }
    }
    if (t >= 240 && t < 240 + XB) {
        int m = t - 240;
        float a = 0.f;
        for (int j = 0; j < NV; ++j) a += xl[m][j] * g[j];
        wl[m] = a;
    }
    __syncthreads();
    for (int idx = t; idx < NCN*NV; idx += 512) {
        int k = idx / NV, j = idx - k*NV;
        Msh[k*132 + j] = Cg[idx];
    }
    __syncthreads();
    if (t < 480) {
        int m = t / 60, kb = t - (t / 60) * 60;
        float4 a0 = {0,0,0,0}, a1 = {0,0,0,0}, a2 = {0,0,0,0}, a3 = {0,0,0,0};
        for (int jg = 0; jg < 30; ++jg) {
            float4 x4 = *(const float4*)&xl[m][jg*4];
            float4 c0 = *(const float4*)&Msh[(kb      ) * 132 + jg*4];
            float4 c1 = *(const float4*)&Msh[(kb + 60 ) * 132 + jg*4];
            float4 c2 = *(const float4*)&Msh[(kb + 120) * 132 + jg*4];
            float4 c3 = *(const float4*)&Msh[(kb + 180) * 132 + jg*4];
            a0.x += x4.x*c0.x; a0.y += x4.y*c0.y; a0.z += x4.z*c0.z; a0.w += x4.w*c0.w;
            a1.x += x4.x*c1.x; a1.y += x4.y*c1.y; a1.z += x4.z*c1.z; a1.w += x4.w*c1.w;
            a2.x += x4.x*c2.x; a2.y += x4.y*c2.y; a2.z += x4.z*c2.z; a2.w += x4.w*c2.w;
            a3.x += x4.x*c3.x; a3.y += x4.y*c3.y; a3.z += x4.z*c3.z; a3.w += x4.w*c3.w;
        }
        #pragma unroll
        for (int p = 0; p < 4; ++p) {
            int k = kb + 60*p;
            float a = (p == 0) ? hadd4(a0) : (p == 1) ? hadd4(a1) : (p == 2) ? hadd4(a2) : hadd4(a3);
            float sn = fmaxf(0.f, c[k] - a);
            float rv = a - c[k] + sn;
            resl[m][k] = rv;
            int b = b0 + m;
            snew[(size_t)b*NCN + k] = sn;
            float so = s[(size_t)b*NCN + k];
            size_t base = (size_t)b * KCAT;
            write2(act, base, k, so);
            write2(act, base, 360 + k, sn);
            write2(act, base, 720 + k, sn - so);
        }
    }
    __syncthreads();
    if (t < XB) {
        float a = 0.f;
        for (int k = 0; k < NCN; ++k) a += resl[t][k] * resl[t][k];
        primal[b0 + t] = sqrtf(a);
    }
    for (int idx = t; idx < NV*NCN; idx += 512) {
        int i = idx / NCN, k = idx - i*NCN;
        Msh[i*244 + k] = CTg[idx];
    }
    __syncthreads();
    if (t < 240) {
        int m = t / 30, ib = t - (t / 30) * 30;
        float4 a0 = {0,0,0,0}, a1 = {0,0,0,0}, a2 = {0,0,0,0}, a3 = {0,0,0,0};
        for (int kg = 0; kg < 60; ++kg) {
            float4 r4 = *(const float4*)&resl[m][kg*4];
            float4 c0 = *(const float4*)&Msh[(ib     ) * 244 + kg*4];
            float4 c1 = *(const float4*)&Msh[(ib + 30) * 244 + kg*4];
            float4 c2 = *(const float4*)&Msh[(ib + 60) * 244 + kg*4];
            float4 c3 = *(const float4*)&Msh[(ib + 90) * 244 + kg*4];
            a0.x += r4.x*c0.x; a0.y += r4.y*c0.y; a0.z += r4.z*c0.z; a0.w += r4.w*c0.w;
            a1.x += r4.x*c1.x; a1.y += r4.y*c1.y; a1.z += r4.z*c1.z; a1.w += r4.w*c1.w;
            a2.x += r4.x*c2.x; a2.y += r4.y*c2.y; a2.z += r4.z*c2.z; a2.w += r4.w*c2.w;
            a3.x += r4.x*c3.x; a3.y += r4.y*c3.y; a3.z += r4.z*c3.z; a3.w += r4.w*c3.w;
        }
        #pragma unroll
        for (int p = 0; p < 4; ++p) {
            int i = ib + 30*p;
            float a = (p == 0) ? hadd4(a0) : (p == 1) ? hadd4(a1) : (p == 2) ? hadd4(a2) : hadd4(a3);
            int b = b0 + m;
            float lo = lam[(size_t)b*NV + i];
            float ln = lo - a;
            lamn[(size_t)b*NV + i] = ln;
            size_t base = (size_t)b * KCAT;
            write2(act, base, 240 + i, lo);
            write2(act, base, 600 + i, ln);
            write2(act, base, 960 + i, ln - lo);
        }
    }
    for (int idx = t; idx < XB*8; idx += 512) {
        int m = idx >> 3, k = 1080 + (idx & 7);
        size_t base = (size_t)(b0 + m) * KCAT;
        act[base + k] = 0;
        act[base + 1088 + k] = 0;
    }
    // fused Gram/v/S partials from xl
    for (int idx = t; idx < NV*NV; idx += 512) {
        int i = idx / NV, j = idx - i*NV;
        double a = 0.0;
        #pragma unroll
        for (int m = 0; m < XB; ++m) a += (double)xl[m][i] * (double)xl[m][j];
        Gp[(size_t)blockIdx.x*NV*NV + idx] = a;
    }
    if (t < NV) {
        double a = 0.0;
        #pragma unroll
        for (int m = 0; m < XB; ++m) a += (double)wl[m] * (double)xl[m][t];
        vp[(size_t)blockIdx.x*NV + t] = a;
    }
    if (t == 0) {
        double a = 0.0;
        #pragma unroll
        for (int m = 0; m < XB; ++m) a += (double)wl[m] * (double)wl[m];
        Sp[blockIdx.x] = a;
    }
}

__global__ void k_qp_red(const double* __restrict__ Gp, const double* __restrict__ vp,
                         const double* __restrict__ Sp,
                         double* __restrict__ G, double* __restrict__ v, double* __restrict__ S) {
    int idx = blockIdx.x * 256 + threadIdx.x;
    if (idx < NV*NV) {
        double a = 0.0;
        for (int p = 0; p < NPART; ++p) a += Gp[(size_t)p*NV*NV + idx];
        G[idx] = a;
    }
    if (idx < NV) {
        double a = 0.0;
        for (int p = 0; p < NPART; ++p) a += vp[(size_t)p*NV + idx];
        v[idx] = a;
    }
    if (idx == 0) {
        double a = 0.0;
        for (int p = 0; p < NPART; ++p) a += Sp[p];
        S[0] = a;
    }
}

// ---------------------------------------------------------------------------
// Merged tail: qp_norm AND fin. 16 batches/block, grid 256.
__global__ __launch_bounds__(256) void k_tail(
        const float* __restrict__ Yb, const double* __restrict__ G,
        const double* __restrict__ v, const double* __restrict__ S,
        float* __restrict__ qp,
        const float* __restrict__ snew, const float* __restrict__ lamn,
        const float* __restrict__ outb,
        float* __restrict__ s, float* __restrict__ lam,
        float* __restrict__ fx) {
    __shared__ float Yl[16][NV];
    __shared__ double tl[16][NV];
    __shared__ float redS[16][17];
    __shared__ float redL[16][17];
    int b0 = blockIdx.x * 16;
    int t = threadIdx.x;
    for (int idx = t; idx < 16*NV; idx += 256) Yl[idx/NV][idx%NV] = Yb[(size_t)b0*NV + idx];
    __syncthreads();
    for (int idx = t; idx < 16*NV; idx += 256) {
        int m = idx / NV, i = idx % NV;
        double a = 0.0;
        for (int j = 0; j < NV; ++j) a += G[j*NV + i] * (double)Yl[m][j];  // G symmetric
        tl[m][i] = a;
    }
    __syncthreads();
    if (t < 16) {
        double a = 0.0, bv = 0.0;
        for (int i = 0; i < NV; ++i) { a += (double)Yl[t][i] * tl[t][i]; bv += (double)Yl[t][i] * v[i]; }
        double q = 0.25 * a + bv + S[0];
        qp[b0 + t] = (float)sqrt(q > 0.0 ? q : 0.0);
    }
    int tm = t / 16;
    int tk = t % 16;
    int b = b0 + tm;
    float ds2 = 0.f, dl2 = 0.f;
    for (int k = tk; k < NCN; k += 16) {
        float o = outb[(size_t)b*NOUTP + k];
        float sf = fmaxf(0.f, snew[(size_t)b*NCN + k] + o);
        float so = s[(size_t)b*NCN + k];
        s[(size_t)b*NCN + k] = sf;
        float d = so - sf;
        ds2 += d * d;
    }
    for (int i = tk; i < NV; i += 16) {
        float o = outb[(size_t)b*NOUTP + NCN + i];
        float lf = lamn[(size_t)b*NV + i] + o;
        float lo = lam[(size_t)b*NV + i];
        lam[(size_t)b*NV + i] = lf;
        float d = lo - lf;
        dl2 += d * d;
    }
    redS[tm][tk] = ds2;
    redL[tm][tk] = dl2;
    __syncthreads();
    if (tk == 0) {
        float a = 0.f, l = 0.f;
        for (int q = 0; q < 16; ++q) { a += redS[tm][q]; l += redL[tm][q]; }
        fx[b] = sqrtf(l) + sqrtf(a);
    }
}

// ---------------------------------------------------------------------------
// Fused GRU cell (round-13 config): tile 64 x 128 x 3 gates, 512 thr (8 waves
// = 2m x 4n), 2-buffer LDS 64KB -> 2 blocks/CU. hi+lo B-reuse pairing.
#define GRUF_STEP(NSLOT, BUFI) do {                                              \
    char* Ah_ = lds + (BUFI) * 32768;                                            \
    char* Al_ = Ah_ + 4096;                                                      \
    char* Bb_ = Ah_ + 8192;                                                      \
    const int srow = lane & 15;                                                  \
    const int ksl = lane >> 4;                                                   \
    short8v ah[2], al[2];                                                        \
    _Pragma("unroll")                                                            \
    for (int fm = 0; fm < 2; ++fm) {                                             \
        int rr = wm * 32 + fm * 16 + srow;                                       \
        int off = rr * 64 + ((ksl ^ ((rr >> 1) & 3)) << 4);                      \
        ah[fm] = *(const short8v*)(Ah_ + off);                                   \
        al[fm] = *(const short8v*)(Al_ + off);                                   \
    }                                                                            \
    _Pragma("unroll")                                                            \
    for (int fn = 0; fn < 2; ++fn) {                                             \
        int rb = wn * 32 + fn * 16 + srow;                                       \
        int boff = rb * 64 + ((ksl ^ ((rb >> 1) & 3)) << 4);                     \
        short8v bfr = *(const short8v*)(Bb_ + boff);                             \
        short8v bfz = *(const short8v*)(Bb_ + 8192 + boff);                      \
        short8v bfn = *(const short8v*)(Bb_ + 16384 + boff);                     \
        _Pragma("unroll")                                                        \
        for (int fm = 0; fm < 2; ++fm) {                                         \
            acc[0][fn][fm] = __builtin_amdgcn_mfma_f32_16x16x32_bf16(ah[fm], bfr, acc[0][fn][fm], 0, 0, 0); \
            acc[0][fn][fm] = __builtin_amdgcn_mfma_f32_16x16x32_bf16(al[fm], bfr, acc[0][fn][fm], 0, 0, 0); \
            acc[1][fn][fm] = __builtin_amdgcn_mfma_f32_16x16x32_bf16(ah[fm], bfz, acc[1][fn][fm], 0, 0, 0); \
            acc[1][fn][fm] = __builtin_amdgcn_mfma_f32_16x16x32_bf16(al[fm], bfz, acc[1][fn][fm], 0, 0, 0); \
            acc[NSLOT][fn][fm] = __builtin_amdgcn_mfma_f32_16x16x32_bf16(ah[fm], bfn, acc[NSLOT][fn][fm], 0, 0, 0); \
            acc[NSLOT][fn][fm] = __builtin_amdgcn_mfma_f32_16x16x32_bf16(al[fm], bfn, acc[NSLOT][fn][fm], 0, 0, 0); \
        }                                                                        \
    }                                                                            \
} while (0)

__global__ __launch_bounds__(512) void k_gruf(
        const u16* __restrict__ act,   // [NB][KCAT]: r filled + h_cur
        const u16* __restrict__ Wc,    // [3*1024][KWC]
        const float* __restrict__ bih, const float* __restrict__ bhh,
        u16* __restrict__ actn) {      // h_new -> h-section
    __shared__ char lds[65536];        // 2 x (A_hi 4K + A_lo 4K + B 24K)
    const int t = threadIdx.x;
    const int lane = t & 63;
    const int wid = t >> 6;          // 0..7
    const int wm = wid >> 2;         // 0..1: 32-row band
    const int wn = wid & 3;          // 0..3: 32-col band per gate
    const int bid = blockIdx.x;
    const int xcd = bid & 7;
    const int slot = bid >> 3;       // 0..63
    const int m0 = (xcd * 8 + (slot & 7)) * 64;
    const int n0 = (slot >> 3) * 128;

    f32x4 acc[4][2][2];
    #pragma unroll
    for (int i = 0; i < 4; ++i)
        #pragma unroll
        for (int j = 0; j < 2; ++j)
            #pragma unroll
            for (int k = 0; k < 2; ++k) {
                f32x4 z = {0.f, 0.f, 0.f, 0.f};
                acc[i][j][k] = z;
            }

    auto stage = [&](int step, int buf) {   // 4 gl16 per thread
        char* Ah_ = lds + buf * 32768;
        char* Al_ = Ah_ + 4096;
        char* Bb_ = Ah_ + 8192;
        const int hiOff = (step < NSTEP_R) ? step * 32 : step * 32 + 1088;
        const int loOff = hiOff + ((step < NSTEP_R) ? 1088 : 1024);
        const int wOff = step * 32;
        {
            int rr = (wid & 3) * 16 + (lane >> 2);     // 0..63
            int kq = ((lane & 3) ^ ((rr >> 1) & 3)) << 3;
            if (wid < 4)
                gl16(act + (size_t)(m0 + rr) * KCAT + hiOff + kq, Ah_ + (wid & 3) * 1024);
            else
                gl16(act + (size_t)(m0 + rr) * KCAT + loOff + kq, Al_ + (wid & 3) * 1024);
        }
        #pragma unroll
        for (int j = 0; j < 3; ++j) {
            int cb = wid * 3 + j;              // 0..23
            int rbg = cb * 16 + (lane >> 2);   // 0..383
            int kq = ((lane & 3) ^ ((rbg >> 1) & 3)) << 3;
            gl16(Wc + (size_t)((rbg >> 7) * 1024 + n0 + (rbg & 127)) * KWC + wOff + kq,
                 Bb_ + cb * 1024);
        }
    };

    stage(0, 0);
    __syncthreads();
    int cur = 0;
    for (int step = 0; step < NSTEP_R; ++step) {       // r-part: n-gate -> i_n
        stage(step + 1, cur ^ 1);
        GRUF_STEP(2, cur);
        __syncthreads();
        cur ^= 1;
    }
    for (int step = NSTEP_R; step < NSTEPS; ++step) {  // h-part: n-gate -> h_n
        if (step + 1 < NSTEPS) stage(step + 1, cur ^ 1);
        GRUF_STEP(3, cur);
        __syncthreads();
        cur ^= 1;
    }

    #pragma unroll
    for (int fn = 0; fn < 2; ++fn) {
        const int jj = n0 + wn * 32 + fn * 16 + (lane & 15);
        const float bir = bih[jj],        bhr = bhh[jj];
        const float biz = bih[1024 + jj], bhz = bhh[1024 + jj];
        const float bin = bih[2048 + jj], bhn = bhh[2048 + jj];
        #pragma unroll
        for (int fm = 0; fm < 2; ++fm) {
            #pragma unroll
            for (int rg = 0; rg < 4; ++rg) {
                int m = m0 + wm * 32 + fm * 16 + (lane >> 4) * 4 + rg;
                float rz = acc[0][fn][fm][rg];
                float zz = acc[1][fn][fm][rg];
                float inn = acc[2][fn][fm][rg];
                float hnn = acc[3][fn][fm][rg];
                float rgate = 1.f / (1.f + expf(-(rz + bir + bhr)));
                float zgate = 1.f / (1.f + expf(-(zz + biz + bhz)));
                float ngate = tanhf(inn + bin + rgate * (hnn + bhn));
                size_t base = (size_t)m * KCAT + HOFF;
                float hv = b2f(act[base + jj]) + b2f(act[base + HIDD + jj]);
                float hnew = (1.f - zgate) * ngate + zgate * hv;
                u16 nh = f2b(hnew);
                actn[base + jj] = nh;
                actn[base + HIDD + jj] = f2b(hnew - b2f(nh));
            }
        }
    }
}

// out = h_new @ W_out^T + b_out; tile 64 x 128, grid (64,3), 2-buf 32KB.
__global__ __launch_bounds__(512) void k_outp(
        const u16* __restrict__ act, const u16* __restrict__ Wo,
        const float* __restrict__ bo, float* __restrict__ outb) {
    __shared__ char lds[32768];        // 2 x (A_hi 4K + A_lo 4K + B 8K)
    const int t = threadIdx.x;
    const int lane = t & 63;
    const int wid = t >> 6;
    const int wm = wid >> 2;           // 0..1
    const int wn = wid & 3;            // 0..3
    const int m0 = blockIdx.x * 64;
    const int n0 = blockIdx.y * 128;
    f32x4 acc[2][2];
    #pragma unroll
    for (int i = 0; i < 2; ++i)
        #pragma unroll
        for (int j = 0; j < 2; ++j) {
            f32x4 z = {0.f, 0.f, 0.f, 0.f};
            acc[i][j] = z;
        }

    auto stage = [&](int step, int buf) {   // 2 gl16 per thread
        char* Ah_ = lds + buf * 16384;
        char* Al_ = Ah_ + 4096;
        char* Bb_ = Ah_ + 8192;
        {
            int rr = (wid & 3) * 16 + (lane >> 2);     // 0..63
            int kq = ((lane & 3) ^ ((rr >> 1) & 3)) << 3;
            if (wid < 4)
                gl16(act + (size_t)(m0 + rr) * KCAT + HOFF + step * 32 + kq,
                     Ah_ + (wid & 3) * 1024);
            else
                gl16(act + (size_t)(m0 + rr) * KCAT + HOFF + HIDD + step * 32 + kq,
                     Al_ + (wid & 3) * 1024);
        }
        {
            int rb = wid * 16 + (lane >> 2);           // 0..127
            int kq = ((lane & 3) ^ ((rb >> 1) & 3)) << 3;
            gl16(Wo + (size_t)(n0 + rb) * KWO + step * 32 + kq, Bb_ + wid * 1024);
        }
    };

    stage(0, 0);
    __syncthreads();
    int cur = 0;
    for (int step = 0; step < 32; ++step) {
        if (step + 1 < 32) stage(step + 1, cur ^ 1);
        {
            char* Ah_ = lds + cur * 16384;
            char* Al_ = Ah_ + 4096;
            char* Bb_ = Ah_ + 8192;
            const int srow = lane & 15;
            const int ksl = lane >> 4;
            short8v ah[2], al[2];
            #pragma unroll
            for (int fm = 0; fm < 2; ++fm) {
                int rr = wm * 32 + fm * 16 + srow;
                int off = rr * 64 + ((ksl ^ ((rr >> 1) & 3)) << 4);
                ah[fm] = *(const short8v*)(Ah_ + off);
                al[fm] = *(const short8v*)(Al_ + off);
            }
            #pragma unroll
            for (int fn = 0; fn < 2; ++fn) {
                int rb = wn * 32 + fn * 16 + srow;
                int boff = rb * 64 + ((ksl ^ ((rb >> 1) & 3)) << 4);
                short8v bf = *(const short8v*)(Bb_ + boff);
                #pragma unroll
                for (int fm = 0; fm < 2; ++fm) {
                    acc[fn][fm] = __builtin_amdgcn_mfma_f32_16x16x32_bf16(ah[fm], bf, acc[fn][fm], 0, 0, 0);
                    acc[fn][fm] = __builtin_amdgcn_mfma_f32_16x16x32_bf16(al[fm], bf, acc[fn][fm], 0, 0, 0);
                }
            }
        }
        __syncthreads();
        cur ^= 1;
    }
    #pragma unroll
    for (int fn = 0; fn < 2; ++fn) {
        int n = n0 + wn * 32 + fn * 16 + (lane & 15);
        if (n < NOUTD) {
            float bb = bo[n];
            #pragma unroll
            for (int fm = 0; fm < 2; ++fm) {
                #pragma unroll
                for (int rg = 0; rg < 4; ++rg) {
                    int m = m0 + wm * 32 + fm * 16 + (lane >> 4) * 4 + rg;
                    outb[(size_t)m * NOUTP + n] = acc[fn][fm][rg] + bb;
                }
            }
        }
    }
}

// ---------------------------------------------------------------------------
extern "C" void kernel_launch(void* const* d_in, const int* in_sizes, int n_in,
                              void* d_out, int out_size, void* d_ws, size_t ws_size,
                              hipStream_t stream) {
    const float* lamda_init = (const float*)d_in[0];
    // d_in[1] = s_init (unused: multiplied by 0 in reference)
    const float* h0    = (const float*)d_in[2];
    const float* H     = (const float*)d_in[3];
    const float* g     = (const float*)d_in[4];
    const float* C     = (const float*)d_in[5];
    const float* c     = (const float*)d_in[6];
    const float* W_ih  = (const float*)d_in[7];
    const float* b_ih  = (const float*)d_in[8];
    const float* W_hh  = (const float*)d_in[9];
    const float* b_hh  = (const float*)d_in[10];
    const float* W_out = (const float*)d_in[11];
    const float* b_out = (const float*)d_in[12];

    float* out    = (float*)d_out;
    float* xi_out = out;                       // [B,120]
    float* primal = out + (size_t)NB*NV;       // [8,B]
    float* fixedo = primal + (size_t)NITER*NB; // [8,B]
    float* qpres  = fixedo + (size_t)NITER*NB; // [8,B]

    char* wp = (char*)d_ws;
    auto alloc = [&](size_t bytes) {
        void* p = (void*)wp;
        wp += (bytes + 255) & ~(size_t)255;
        return p;
    };
    float* Amat  = (float*)alloc(NV*NV*4);
    float* A0m   = (float*)alloc(NV*NV*4);
    float* Qinv  = (float*)alloc(NV*NV*4);
    float* Qinv0 = (float*)alloc(NV*NV*4);
    float* CTg   = (float*)alloc((size_t)NV*NCN*4);
    float* s0v   = (float*)alloc(NCN*4);
    float* sbuf  = (float*)alloc((size_t)NB*NCN*4);
    float* snew  = (float*)alloc((size_t)NB*NCN*4);
    float* lam   = (float*)alloc((size_t)NB*NV*4);
    float* lamn  = (float*)alloc((size_t)NB*NV*4);
    float* xib   = (float*)alloc((size_t)NB*NV*4);
    float* Yb    = (float*)alloc((size_t)NB*NV*4);
    float* outb  = (float*)alloc((size_t)NB*NOUTP*4);
    u16* actA    = (u16*)alloc((size_t)NB*KCAT*2);
    u16* actB    = (u16*)alloc((size_t)NB*KCAT*2);
    u16* Wcat    = (u16*)alloc((size_t)3072*KWC*2);
    u16* Wopk    = (u16*)alloc((size_t)NOUTP*KWO*2);
    double* Gpart = (double*)alloc((size_t)NPART*NV*NV*8);
    double* vpart = (double*)alloc((size_t)NPART*NV*8);
    double* Spart = (double*)alloc(NPART*8);
    double* Gfin  = (double*)alloc(NV*NV*8);
    double* vfin  = (double*)alloc(NV*8);
    double* Sfin  = (double*)alloc(8);

    k_buildA<<<dim3(NV, 2), dim3(128), 0, stream>>>(H, C, Amat, A0m);
    k_buildCT<<<dim3(NV), dim3(256), 0, stream>>>(C, CTg);
    k_invert<<<dim3(2), dim3(1024), 0, stream>>>(Amat, A0m, Qinv, Qinv0);
    k_s0<<<dim3(1), dim3(256), 0, stream>>>(Qinv0, g, C, c, s0v);
    k_init<<<dim3(NB/8), dim3(256), 0, stream>>>(s0v, lamda_init, sbuf, lam);
    k_packWcat<<<dim3(3072), dim3(256), 0, stream>>>(W_ih, W_hh, Wcat);
    k_packWo<<<dim3(NOUTP), dim3(256), 0, stream>>>(W_out, Wopk);
    k_packH<<<dim3(NB), dim3(256), 0, stream>>>(h0, actA);

    u16* hc = actA;
    u16* hn2 = actB;
    for (int it = 0; it < NITER; ++it) {
        k_xiproj<<<dim3(NB/XB), dim3(512), 0, stream>>>(sbuf, lam, C, CTg, c, g, Qinv, H,
                                                        xib, Yb, snew, lamn, hc,
                                                        primal + (size_t)it*NB,
                                                        Gpart, vpart, Spart);
        k_qp_red<<<dim3((NV*NV + 255)/256), dim3(256), 0, stream>>>(Gpart, vpart, Spart, Gfin, vfin, Sfin);
        k_gruf<<<dim3(512), dim3(512), 0, stream>>>(hc, Wcat, b_ih, b_hh, hn2);
        k_outp<<<dim3(64, 3), dim3(512), 0, stream>>>(hn2, Wopk, b_out, outb);
        k_tail<<<dim3(NB/16), dim3(256), 0, stream>>>(Yb, Gfin, vfin, Sfin,
                                                      qpres + (size_t)it*NB,
                                                      snew, lamn, outb, sbuf, lam,
                                                      fixedo + (size_t)it*NB);
        u16* tmp = hc; hc = hn2; hn2 = tmp;
    }
    hipMemcpyAsync(xi_out, xib, (size_t)NB*NV*sizeof(float), hipMemcpyDeviceToDevice, stream);
}

// Round 16
// 2167.893 us; speedup vs baseline: 1.1047x; 1.0670x over previous
//
#include <hip/hip_runtime.h>
#include <hip/hip_bf16.h>
#include <math.h>

// Problem constants (match reference)
#define NB    4096   // num_batch
#define NV    120    // NVAR
#define NCN   240    // num constraints
#define HIDD  1024   // GRU hidden
#define RINN  1080   // GRU input dim
#define NOUTD 360    // NC+NVAR
#define NOUTP 384    // padded out cols
#define NITER 8
#define REGEPS 1e-4f
#define NPART 128    // Gram partial blocks (32 batches each), FLOAT partials

// 2-term split: activations [hi|lo] (exact), weights stored ONCE (hi).
// GEMMs consume BOTH a_hi and a_lo (r14 ablation: dropping a_lo regressed).
// act row: [r_hi 1088 | r_lo 1088 | h_hi 1024 | h_lo 1024] = 4224
// Wcat row: [Wih_hi 1088 | Whh_hi 1024] = 2112 (B-reuse pairing)
#define KCAT 4224
#define HOFF 2176    // h section start within an act row
#define KWC  2112    // Wcat K
#define KWO  1024    // W_out packed K
#define NSTEP_R 34   // r-section 32-wide K-steps (1088/32)
#define NSTEPS  66   // total (2112/32)

typedef unsigned short u16;
typedef __attribute__((ext_vector_type(8))) short short8v;
typedef __attribute__((ext_vector_type(4))) float f32x4;

__device__ inline u16 f2b(float x) {
    __hip_bfloat16 h = __float2bfloat16(x);
    return __builtin_bit_cast(u16, h);
}
__device__ inline float b2f(u16 u) {
    __hip_bfloat16 h = __builtin_bit_cast(__hip_bfloat16, u);
    return __bfloat162float(h);
}

// async global -> LDS, 16B per lane (wave-uniform LDS base + lane*16)
__device__ inline void gl16(const void* g, void* l) {
    __builtin_amdgcn_global_load_lds(
        (__attribute__((address_space(1))) void*)(void*)g,
        (__attribute__((address_space(3))) void*)l, 16, 0, 0);
}

// ---------------------------------------------------------------------------
// Build A = H + C^T C + REG*I (which==0) and A0 = H + REG*I (which==1)
__global__ void k_buildA(const float* __restrict__ H, const float* __restrict__ C,
                         float* __restrict__ A, float* __restrict__ A0) {
    int i = blockIdx.x;
    int which = blockIdx.y;
    for (int j = threadIdx.x; j < NV; j += blockDim.x) {
        float v = H[i*NV + j] + (i == j ? REGEPS : 0.f);
        if (which == 0) {
            float acc = 0.f;
            for (int k = 0; k < NCN; ++k) acc += C[k*NV + i] * C[k*NV + j];
            A[i*NV + j] = v + acc;   // RHO = 1
        } else {
            A0[i*NV + j] = v;
        }
    }
}

// CT[j][k] = C[k][j]
__global__ void k_buildCT(const float* __restrict__ C, float* __restrict__ CT) {
    int j = blockIdx.x;   // 0..119
    for (int k = threadIdx.x; k < NCN; k += 256)
        CT[(size_t)j * NCN + k] = C[(size_t)k * NV + j];
}

// Row-major 4x4 inverse via 2x2-subdeterminant adjugate (ILP-friendly).
__device__ inline void inv4x4(const float* m, float* inv) {
    float s0 = m[0]*m[5] - m[1]*m[4];
    float s1 = m[0]*m[6] - m[2]*m[4];
    float s2 = m[0]*m[7] - m[3]*m[4];
    float s3 = m[1]*m[6] - m[2]*m[5];
    float s4 = m[1]*m[7] - m[3]*m[5];
    float s5 = m[2]*m[7] - m[3]*m[6];
    float c5 = m[10]*m[15] - m[11]*m[14];
    float c4 = m[9]*m[15] - m[11]*m[13];
    float c3 = m[9]*m[14] - m[10]*m[13];
    float c2 = m[8]*m[15] - m[11]*m[12];
    float c1 = m[8]*m[14] - m[10]*m[12];
    float c0 = m[8]*m[13] - m[9]*m[12];
    float det = s0*c5 - s1*c4 + s2*c3 + s3*c2 - s4*c1 + s5*c0;
    float id = 1.0f / det;
    inv[0]  = ( m[5]*c5 - m[6]*c4 + m[7]*c3) * id;
    inv[1]  = (-m[1]*c5 + m[2]*c4 - m[3]*c3) * id;
    inv[2]  = ( m[13]*s5 - m[14]*s4 + m[15]*s3) * id;
    inv[3]  = (-m[9]*s5 + m[10]*s4 - m[11]*s3) * id;
    inv[4]  = (-m[4]*c5 + m[6]*c2 - m[7]*c1) * id;
    inv[5]  = ( m[0]*c5 - m[2]*c2 + m[3]*c1) * id;
    inv[6]  = (-m[12]*s5 + m[14]*s2 - m[15]*s1) * id;
    inv[7]  = ( m[8]*s5 - m[10]*s2 + m[11]*s1) * id;
    inv[8]  = ( m[4]*c4 - m[5]*c2 + m[7]*c0) * id;
    inv[9]  = (-m[0]*c4 + m[1]*c2 - m[3]*c0) * id;
    inv[10] = ( m[12]*s4 - m[13]*s2 + m[15]*s0) * id;
    inv[11] = (-m[8]*s4 + m[9]*s2 - m[11]*s0) * id;
    inv[12] = (-m[4]*c3 + m[5]*c1 - m[6]*c0) * id;
    inv[13] = ( m[0]*c3 - m[1]*c1 + m[2]*c0) * id;
    inv[14] = (-m[12]*s3 + m[13]*s1 - m[14]*s0) * id;
    inv[15] = ( m[8]*s3 - m[9]*s1 + m[10]*s0) * id;
}

// Blocked rank-4 Gauss-Jordan, phase-split. 2 barriers/chunk, 30 chunks.
__global__ __launch_bounds__(1024) void k_invert(const float* __restrict__ Ain,
                                                 const float* __restrict__ A0in,
                                                 float* __restrict__ Qi,
                                                 float* __restrict__ Qi0) {
    __shared__ float M[NV][132];
    __shared__ float Rl[4][132];
    __shared__ float Bl[16];
    const float* src = (blockIdx.x == 0) ? Ain : A0in;
    float* dst = (blockIdx.x == 0) ? Qi : Qi0;
    const int t = threadIdx.x;
    for (int idx = t; idx < NV*132; idx += 1024) {
        int i = idx / 132, j = idx - i*132;
        M[i][j] = (j < NV) ? src[i*NV + j] : 0.f;
    }
    __syncthreads();
    const int ty = t >> 5;        // 0..31 row owner (4 rows each)
    const int g4 = (t & 31) * 4;  // col group 0..124
    for (int kk = 0; kk < NV; kk += 4) {
        if (ty == 0) {
            float a[16], b[16];
            #pragma unroll
            for (int p = 0; p < 4; ++p) {
                float4 v = *(const float4*)&M[kk + p][kk];
                a[p*4+0] = v.x; a[p*4+1] = v.y; a[p*4+2] = v.z; a[p*4+3] = v.w;
            }
            inv4x4(a, b);
            float4 m0v = *(const float4*)&M[kk+0][g4];
            float4 m1v = *(const float4*)&M[kk+1][g4];
            float4 m2v = *(const float4*)&M[kk+2][g4];
            float4 m3v = *(const float4*)&M[kk+3][g4];
            #pragma unroll
            for (int p = 0; p < 4; ++p) {
                float4 r;
                r.x = b[p*4+0]*m0v.x + b[p*4+1]*m1v.x + b[p*4+2]*m2v.x + b[p*4+3]*m3v.x;
                r.y = b[p*4+0]*m0v.y + b[p*4+1]*m1v.y + b[p*4+2]*m2v.y + b[p*4+3]*m3v.y;
                r.z = b[p*4+0]*m0v.z + b[p*4+1]*m1v.z + b[p*4+2]*m2v.z + b[p*4+3]*m3v.z;
                r.w = b[p*4+0]*m0v.w + b[p*4+1]*m1v.w + b[p*4+2]*m2v.w + b[p*4+3]*m3v.w;
                *(float4*)&Rl[p][g4] = r;
            }
            if (t < 16) Bl[t] = b[t];
        }
        float4 F[4];
        #pragma unroll
        for (int q = 0; q < 4; ++q) {
            int i = ty + 32*q;
            F[q] = (i < NV) ? *(const float4*)&M[i][kk] : float4{0.f,0.f,0.f,0.f};
        }
        __syncthreads();
        #pragma unroll
        for (int q = 0; q < 4; ++q) {
            int i = ty + 32*q;
            if (i < NV) {
                int dp = i - kk;
                bool ispiv = (dp >= 0) && (dp < 4);
                float4 v;
                if (g4 == kk) {
                    if (ispiv) {
                        v = *(const float4*)&Bl[dp*4];
                    } else {
                        v.x = -(F[q].x*Bl[0] + F[q].y*Bl[4] + F[q].z*Bl[8]  + F[q].w*Bl[12]);
                        v.y = -(F[q].x*Bl[1] + F[q].y*Bl[5] + F[q].z*Bl[9]  + F[q].w*Bl[13]);
                        v.z = -(F[q].x*Bl[2] + F[q].y*Bl[6] + F[q].z*Bl[10] + F[q].w*Bl[14]);
                        v.w = -(F[q].x*Bl[3] + F[q].y*Bl[7] + F[q].z*Bl[11] + F[q].w*Bl[15]);
                    }
                } else if (ispiv) {
                    v = *(const float4*)&Rl[dp][g4];
                } else {
                    float4 r0 = *(const float4*)&Rl[0][g4];
                    float4 r1 = *(const float4*)&Rl[1][g4];
                    float4 r2 = *(const float4*)&Rl[2][g4];
                    float4 r3 = *(const float4*)&Rl[3][g4];
                    v = *(const float4*)&M[i][g4];
                    v.x -= F[q].x*r0.x + F[q].y*r1.x + F[q].z*r2.x + F[q].w*r3.x;
                    v.y -= F[q].x*r0.y + F[q].y*r1.y + F[q].z*r2.y + F[q].w*r3.y;
                    v.z -= F[q].x*r0.z + F[q].y*r1.z + F[q].z*r2.z + F[q].w*r3.z;
                    v.w -= F[q].x*r0.w + F[q].y*r1.w + F[q].z*r2.w + F[q].w*r3.w;
                }
                *(float4*)&M[i][g4] = v;
            }
        }
        __syncthreads();
    }
    for (int idx = t; idx < NV*NV; idx += 1024) {
        int i = idx / NV, j = idx - i*NV;
        dst[idx] = M[i][j];
    }
}

// xi0 = (-g) @ Qinv0^T ; s0 = max(0, c - C xi0)   (batch-constant vectors)
__global__ void k_s0(const float* __restrict__ Qi0, const float* __restrict__ g,
                     const float* __restrict__ C, const float* __restrict__ c,
                     float* __restrict__ s0v) {
    __shared__ float xi0[NV];
    int t = threadIdx.x;
    if (t < NV) {
        float a = 0.f;
        for (int j = 0; j < NV; ++j) a += Qi0[t*NV + j] * g[j];
        xi0[t] = -a;
    }
    __syncthreads();
    if (t < NCN) {
        float a = 0.f;
        for (int j = 0; j < NV; ++j) a += C[t*NV + j] * xi0[j];
        s0v[t] = fmaxf(0.f, c[t] - a);
    }
}

// Initialize state: s = broadcast(s0), lam = lamda_init
__global__ void k_init(const float* __restrict__ s0v, const float* __restrict__ lam0,
                       float* __restrict__ s, float* __restrict__ lam) {
    int b0 = blockIdx.x * 8;
    int t = threadIdx.x;
    for (int idx = t; idx < 8*NCN; idx += 256) {
        int m = idx / NCN, k = idx % NCN;
        s[(size_t)(b0 + m)*NCN + k] = s0v[k];
    }
    for (int idx = t; idx < 8*NV; idx += 256) lam[(size_t)b0*NV + idx] = lam0[(size_t)b0*NV + idx];
}

// Pack h0 into act buffer h-section: [h_hi | h_lo]
__global__ void k_packH(const float* __restrict__ h0, u16* __restrict__ act) {
    int n = blockIdx.x;
    size_t base = (size_t)n * KCAT + HOFF;
    for (int k = threadIdx.x; k < HIDD; k += 256) {
        float x = h0[(size_t)n * HIDD + k];
        u16 hi = f2b(x);
        act[base + k] = hi;
        act[base + HIDD + k] = f2b(x - b2f(hi));
    }
}

// Pack Wih+Whh (hi only, once): [Wih_hi 1088 | Whh_hi 1024]
__global__ void k_packWcat(const float* __restrict__ Wih, const float* __restrict__ Whh,
                           u16* __restrict__ Wc) {
    int n = blockIdx.x;   // 0..3071
    size_t base = (size_t)n * KWC;
    for (int k = threadIdx.x; k < 1088; k += 256)
        Wc[base + k] = f2b(k < RINN ? Wih[(size_t)n * RINN + k] : 0.f);
    for (int k = threadIdx.x; k < HIDD; k += 256)
        Wc[base + 1088 + k] = f2b(Whh[(size_t)n * HIDD + k]);
}

// Pack W_out (hi only): [NOUTP rows][1024]
__global__ void k_packWo(const float* __restrict__ src, u16* __restrict__ dst) {
    int n = blockIdx.x;
    size_t row = (size_t)n * KWO;
    for (int k = threadIdx.x; k < KWO; k += 256)
        dst[row + k] = f2b(n < NOUTD ? src[(size_t)n * HIDD + k] : 0.f);
}

__device__ inline void write2(u16* __restrict__ act, size_t base, int pos, float x) {
    u16 hi = f2b(x);
    u16 lo = f2b(x - b2f(hi));
    act[base + pos] = hi;
    act[base + 1088 + pos] = lo;
}

__device__ inline float hadd4(float4 v) { return (v.x + v.y) + (v.z + v.w); }

// ---------------------------------------------------------------------------
// Fused: xi solve + projection + GRU-input pack. XB=16 batches/block,
// 256 blocks (one CU-round; r15 ran 512 blocks = 2 rounds with the same
// per-block staging cost). bd overlays resl (disjoint live ranges).
// LDS: 126.7K Msh + 15.4K resl + 7.7K ul + 7.7K xl = 157.4KB.
#define XB 16
__global__ __launch_bounds__(512) void k_xiproj(
        const float* __restrict__ s, const float* __restrict__ lam,
        const float* __restrict__ Cg, const float* __restrict__ CTg,
        const float* __restrict__ c,
        const float* __restrict__ g, const float* __restrict__ Qi,
        const float* __restrict__ Hg,
        float* __restrict__ xi, float* __restrict__ Y, float* __restrict__ wv,
        float* __restrict__ snew, float* __restrict__ lamn,
        u16* __restrict__ act, float* __restrict__ primal) {
    __shared__ float Msh[31680];      // C/QH: [240][132]; CT: [120][244]
    __shared__ float resl[XB][NCN];   // phase5/6 residuals; ALSO bd in phase2
    __shared__ float ul[XB][NV];
    __shared__ float xl[XB][NV];
    const int b0 = blockIdx.x * XB;
    const int t = threadIdx.x;
    #define bd resl

    // stage CT + bd
    for (int idx = t; idx < XB*NCN; idx += 512) {
        int m = idx / NCN, k = idx - m*NCN;
        bd[m][k] = c[k] - s[(size_t)(b0 + m)*NCN + k];
    }
    for (int idx = t; idx < NV*NCN; idx += 512) {
        int i = idx / NCN, k = idx - i*NCN;
        Msh[i*244 + k] = CTg[idx];
    }
    __syncthreads();
    // phase 2: ul_j = lam_j - g_j + sum_k bd_k CT[j][k]
    if (t < 480) {
        int m = t / 30, jb = t - (t / 30) * 30;
        float4 a0 = {0,0,0,0}, a1 = {0,0,0,0}, a2 = {0,0,0,0}, a3 = {0,0,0,0};
        for (int kg = 0; kg < 60; ++kg) {
            float4 b4 = *(const float4*)&bd[m][kg*4];
            float4 c0 = *(const float4*)&Msh[(jb     ) * 244 + kg*4];
            float4 c1 = *(const float4*)&Msh[(jb + 30) * 244 + kg*4];
            float4 c2 = *(const float4*)&Msh[(jb + 60) * 244 + kg*4];
            float4 c3 = *(const float4*)&Msh[(jb + 90) * 244 + kg*4];
            a0.x += b4.x*c0.x; a0.y += b4.y*c0.y; a0.z += b4.z*c0.z; a0.w += b4.w*c0.w;
            a1.x += b4.x*c1.x; a1.y += b4.y*c1.y; a1.z += b4.z*c1.z; a1.w += b4.w*c1.w;
            a2.x += b4.x*c2.x; a2.y += b4.y*c2.y; a2.z += b4.z*c2.z; a2.w += b4.w*c2.w;
            a3.x += b4.x*c3.x; a3.y += b4.y*c3.y; a3.z += b4.z*c3.z; a3.w += b4.w*c3.w;
        }
        #pragma unroll
        for (int p = 0; p < 4; ++p) {
            int j = jb + 30*p;
            float h = (p == 0) ? hadd4(a0) : (p == 1) ? hadd4(a1) : (p == 2) ? hadd4(a2) : hadd4(a3);
            ul[m][j] = lam[(size_t)(b0 + m)*NV + j] - g[j] + h;
        }
    }
    __syncthreads();
    // stage Qinv (rows 0..119) + H (rows 120..239), stride 132
    for (int idx = t; idx < NV*NV; idx += 512) {
        int i = idx / NV, j = idx - i*NV;
        Msh[i*132 + j] = Qi[idx];
        Msh[(120 + i)*132 + j] = Hg[idx];
    }
    __syncthreads();
    // phase 3: xi_i = sum_j Qinv[i][j] ul_j
    if (t < 480) {
        int m = t / 30, ib = t - (t / 30) * 30;
        float4 a0 = {0,0,0,0}, a1 = {0,0,0,0}, a2 = {0,0,0,0}, a3 = {0,0,0,0};
        for (int jg = 0; jg < 30; ++jg) {
            float4 u4 = *(const float4*)&ul[m][jg*4];
            float4 q0 = *(const float4*)&Msh[(ib     ) * 132 + jg*4];
            float4 q1 = *(const float4*)&Msh[(ib + 30) * 132 + jg*4];
            float4 q2 = *(const float4*)&Msh[(ib + 60) * 132 + jg*4];
            float4 q3 = *(const float4*)&Msh[(ib + 90) * 132 + jg*4];
            a0.x += u4.x*q0.x; a0.y += u4.y*q0.y; a0.z += u4.z*q0.z; a0.w += u4.w*q0.w;
            a1.x += u4.x*q1.x; a1.y += u4.y*q1.y; a1.z += u4.z*q1.z; a1.w += u4.w*q1.w;
            a2.x += u4.x*q2.x; a2.y += u4.y*q2.y; a2.z += u4.z*q2.z; a2.w += u4.w*q2.w;
            a3.x += u4.x*q3.x; a3.y += u4.y*q3.y; a3.z += u4.z*q3.z; a3.w += u4.w*q3.w;
        }
        #pragma unroll
        for (int p = 0; p < 4; ++p) {
            int i = ib + 30*p;
            float a = (p == 0) ? hadd4(a0) : (p == 1) ? hadd4(a1) : (p == 2) ? hadd4(a2) : hadd4(a3);
            xl[m][i] = a;
            xi[(size_t)(b0 + m)*NV + i] = a;
        }
    }
    __syncthreads();
    // phase 4: Y_i = sum_j xl_j H[i][j]; wv = xl . g
    if (t < 480) {
        int m = t / 30, ib = t - (t / 30) * 30;
        float4 a0 = {0,0,0,0}, a1 = {0,0,0,0}, a2 = {0,0,0,0}, a3 = {0,0,0,0};
        for (int jg = 0; jg < 30; ++jg) {
            float4 x4 = *(const float4*)&xl[m][jg*4];
            float4 h0 = *(const float4*)&Msh[(120 + ib     ) * 132 + jg*4];
            float4 h1 = *(const float4*)&Msh[(120 + ib + 30) * 132 + jg*4];
            float4 h2 = *(const float4*)&Msh[(120 + ib + 60) * 132 + jg*4];
            float4 h3 = *(const float4*)&Msh[(120 + ib + 90) * 132 + jg*4];
            a0.x += x4.x*h0.x; a0.y += x4.y*h0.y; a0.z += x4.z*h0.z; a0.w += x4.w*h0.w;
            a1.x += x4.x*h1.x; a1.y += x4.y*h1.y; a1.z += x4.z*h1.z; a1.w += x4.w*h1.w;
            a2.x += x4.x*h2.x; a2.y += x4.y*h2.y; a2.z += x4.z*h2.z; a2.w += x4.w*h2.w;
            a3.x += x4.x*h3.x; a3.y += x4.y*h3.y; a3.z += x4.z*h3.z; a3.w += x4.w*h3.w;
        }
        #pragma unroll
        for (int p = 0; p < 4; ++p) {
            int i = ib + 30*p;
            float a = (p == 0) ? hadd4(a0) : (p == 1) ? hadd4(a1) : (p == 2) ? hadd4(a2) : hadd4(a3);
            Y[(size_t)(b0 + m)*NV + i] = a;
        }
    }
    if (t >= 480 && t < 480 + XB) {
        int m = t - 480;
        float a = 0.f;
        for (int j = 0; j < NV; ++j) a += xl[m][j] * g[j];
        wv[b0 + m] = a;
    }
    __syncthreads();
    // stage C (rows 0..239, stride 132)
    for (int idx = t; idx < NCN*NV; idx += 512) {
        int k = idx / NV, j = idx - k*NV;
        Msh[k*132 + j] = Cg[idx];
    }
    __syncthreads();
    // phase 5: Axi_k -> s_new, res, r-pack(s). 960 slots, 2 passes.
    for (int s5 = t; s5 < XB*60; s5 += 512) {
        int m = s5 / 60, kb = s5 - (s5 / 60) * 60;
        float4 a0 = {0,0,0,0}, a1 = {0,0,0,0}, a2 = {0,0,0,0}, a3 = {0,0,0,0};
        for (int jg = 0; jg < 30; ++jg) {
            float4 x4 = *(const float4*)&xl[m][jg*4];
            float4 c0 = *(const float4*)&Msh[(kb      ) * 132 + jg*4];
            float4 c1 = *(const float4*)&Msh[(kb + 60 ) * 132 + jg*4];
            float4 c2 = *(const float4*)&Msh[(kb + 120) * 132 + jg*4];
            float4 c3 = *(const float4*)&Msh[(kb + 180) * 132 + jg*4];
            a0.x += x4.x*c0.x; a0.y += x4.y*c0.y; a0.z += x4.z*c0.z; a0.w += x4.w*c0.w;
            a1.x += x4.x*c1.x; a1.y += x4.y*c1.y; a1.z += x4.z*c1.z; a1.w += x4.w*c1.w;
            a2.x += x4.x*c2.x; a2.y += x4.y*c2.y; a2.z += x4.z*c2.z; a2.w += x4.w*c2.w;
            a3.x += x4.x*c3.x; a3.y += x4.y*c3.y; a3.z += x4.z*c3.z; a3.w += x4.w*c3.w;
        }
        #pragma unroll
        for (int p = 0; p < 4; ++p) {
            int k = kb + 60*p;
            float a = (p == 0) ? hadd4(a0) : (p == 1) ? hadd4(a1) : (p == 2) ? hadd4(a2) : hadd4(a3);
            float sn = fmaxf(0.f, c[k] - a);
            float rv = a - c[k] + sn;
            resl[m][k] = rv;
            int b = b0 + m;
            snew[(size_t)b*NCN + k] = sn;
            float so = s[(size_t)b*NCN + k];
            size_t base = (size_t)b * KCAT;
            write2(act, base, k, so);
            write2(act, base, 360 + k, sn);
            write2(act, base, 720 + k, sn - so);
        }
    }
    __syncthreads();
    // restage CT + primal
    if (t < XB) {
        float a = 0.f;
        for (int k = 0; k < NCN; ++k) a += resl[t][k] * resl[t][k];
        primal[b0 + t] = sqrtf(a);
    }
    for (int idx = t; idx < NV*NCN; idx += 512) {
        int i = idx / NCN, k = idx - i*NCN;
        Msh[i*244 + k] = CTg[idx];
    }
    __syncthreads();
    // phase 6: lam update + r-pack(lam)
    if (t < 480) {
        int m = t / 30, ib = t - (t / 30) * 30;
        float4 a0 = {0,0,0,0}, a1 = {0,0,0,0}, a2 = {0,0,0,0}, a3 = {0,0,0,0};
        for (int kg = 0; kg < 60; ++kg) {
            float4 r4 = *(const float4*)&resl[m][kg*4];
            float4 c0 = *(const float4*)&Msh[(ib     ) * 244 + kg*4];
            float4 c1 = *(const float4*)&Msh[(ib + 30) * 244 + kg*4];
            float4 c2 = *(const float4*)&Msh[(ib + 60) * 244 + kg*4];
            float4 c3 = *(const float4*)&Msh[(ib + 90) * 244 + kg*4];
            a0.x += r4.x*c0.x; a0.y += r4.y*c0.y; a0.z += r4.z*c0.z; a0.w += r4.w*c0.w;
            a1.x += r4.x*c1.x; a1.y += r4.y*c1.y; a1.z += r4.z*c1.z; a1.w += r4.w*c1.w;
            a2.x += r4.x*c2.x; a2.y += r4.y*c2.y; a2.z += r4.z*c2.z; a2.w += r4.w*c2.w;
            a3.x += r4.x*c3.x; a3.y += r4.y*c3.y; a3.z += r4.z*c3.z; a3.w += r4.w*c3.w;
        }
        #pragma unroll
        for (int p = 0; p < 4; ++p) {
            int i = ib + 30*p;
            float a = (p == 0) ? hadd4(a0) : (p == 1) ? hadd4(a1) : (p == 2) ? hadd4(a2) : hadd4(a3);
            int b = b0 + m;
            float lo = lam[(size_t)b*NV + i];
            float ln = lo - a;
            lamn[(size_t)b*NV + i] = ln;
            size_t base = (size_t)b * KCAT;
            write2(act, base, 240 + i, lo);
            write2(act, base, 600 + i, ln);
            write2(act, base, 960 + i, ln - lo);
        }
    }
    for (int idx = t; idx < XB*8; idx += 512) {
        int m = idx >> 3, k = 1080 + (idx & 7);
        size_t base = (size_t)(b0 + m) * KCAT;
        act[base + k] = 0;
        act[base + 1088 + k] = 0;
    }
    #undef bd
}

// Partial Gram (FLOAT partials): 128 blocks x 32 batches.
__global__ __launch_bounds__(256) void k_qp_part(const float* __restrict__ xi, const float* __restrict__ wv,
                         float* __restrict__ Gp, float* __restrict__ vp, float* __restrict__ Sp) {
    __shared__ float xl[32][NV];
    __shared__ float wl[32];
    int p = blockIdx.x;
    int b0 = p * 32;
    int t = threadIdx.x;
    for (int idx = t; idx < 32*NV; idx += 256) xl[idx/NV][idx%NV] = xi[(size_t)b0*NV + idx];
    if (t < 32) wl[t] = wv[b0 + t];
    __syncthreads();
    for (int idx = t; idx < NV*NV; idx += 256) {
        int i = idx / NV, j = idx % NV;
        float a = 0.f;
        #pragma unroll
        for (int m = 0; m < 32; ++m) a += xl[m][i] * xl[m][j];
        Gp[(size_t)p*NV*NV + idx] = a;
    }
    if (t < NV) {
        float a = 0.f;
        #pragma unroll
        for (int m = 0; m < 32; ++m) a += wl[m] * xl[m][t];
        vp[(size_t)p*NV + t] = a;
    }
    if (t == 0) {
        float a = 0.f;
        #pragma unroll
        for (int m = 0; m < 32; ++m) a += wl[m] * wl[m];
        Sp[p] = a;
    }
}

__global__ void k_qp_red(const float* __restrict__ Gp, const float* __restrict__ vp,
                         const float* __restrict__ Sp,
                         double* __restrict__ G, double* __restrict__ v, double* __restrict__ S) {
    int idx = blockIdx.x * 256 + threadIdx.x;
    if (idx < NV*NV) {
        double a = 0.0;
        for (int p = 0; p < NPART; ++p) a += (double)Gp[(size_t)p*NV*NV + idx];
        G[idx] = a;
    }
    if (idx < NV) {
        double a = 0.0;
        for (int p = 0; p < NPART; ++p) a += (double)vp[(size_t)p*NV + idx];
        v[idx] = a;
    }
    if (idx == 0) {
        double a = 0.0;
        for (int p = 0; p < NPART; ++p) a += (double)Sp[p];
        S[0] = a;
    }
}

// ---------------------------------------------------------------------------
// Merged tail: qp_norm AND fin. 16 batches/block, grid 256.
__global__ __launch_bounds__(256) void k_tail(
        const float* __restrict__ Yb, const double* __restrict__ G,
        const double* __restrict__ v, const double* __restrict__ S,
        float* __restrict__ qp,
        const float* __restrict__ snew, const float* __restrict__ lamn,
        const float* __restrict__ outb,
        float* __restrict__ s, float* __restrict__ lam,
        float* __restrict__ fx) {
    __shared__ float Yl[16][NV];
    __shared__ double tl[16][NV];
    __shared__ float redS[16][17];
    __shared__ float redL[16][17];
    int b0 = blockIdx.x * 16;
    int t = threadIdx.x;
    for (int idx = t; idx < 16*NV; idx += 256) Yl[idx/NV][idx%NV] = Yb[(size_t)b0*NV + idx];
    __syncthreads();
    for (int idx = t; idx < 16*NV; idx += 256) {
        int m = idx / NV, i = idx % NV;
        double a = 0.0;
        for (int j = 0; j < NV; ++j) a += G[j*NV + i] * (double)Yl[m][j];  // G symmetric
        tl[m][i] = a;
    }
    __syncthreads();
    if (t < 16) {
        double a = 0.0, bv = 0.0;
        for (int i = 0; i < NV; ++i) { a += (double)Yl[t][i] * tl[t][i]; bv += (double)Yl[t][i] * v[i]; }
        double q = 0.25 * a + bv + S[0];
        qp[b0 + t] = (float)sqrt(q > 0.0 ? q : 0.0);
    }
    int tm = t / 16;
    int tk = t % 16;
    int b = b0 + tm;
    float ds2 = 0.f, dl2 = 0.f;
    for (int k = tk; k < NCN; k += 16) {
        float o = outb[(size_t)b*NOUTP + k];
        float sf = fmaxf(0.f, snew[(size_t)b*NCN + k] + o);
        float so = s[(size_t)b*NCN + k];
        s[(size_t)b*NCN + k] = sf;
        float d = so - sf;
        ds2 += d * d;
    }
    for (int i = tk; i < NV; i += 16) {
        float o = outb[(size_t)b*NOUTP + NCN + i];
        float lf = lamn[(size_t)b*NV + i] + o;
        float lo = lam[(size_t)b*NV + i];
        lam[(size_t)b*NV + i] = lf;
        float d = lo - lf;
        dl2 += d * d;
    }
    redS[tm][tk] = ds2;
    redL[tm][tk] = dl2;
    __syncthreads();
    if (tk == 0) {
        float a = 0.f, l = 0.f;
        for (int q = 0; q < 16; ++q) { a += redS[tm][q]; l += redL[tm][q]; }
        fx[b] = sqrtf(l) + sqrtf(a);
    }
}

// ---------------------------------------------------------------------------
// Fused GRU cell (round-13 config): tile 64 x 128 x 3 gates, 512 thr (8 waves
// = 2m x 4n), 2-buffer LDS 64KB -> 2 blocks/CU. hi+lo B-reuse pairing.
#define GRUF_STEP(NSLOT, BUFI) do {                                              \
    char* Ah_ = lds + (BUFI) * 32768;                                            \
    char* Al_ = Ah_ + 4096;                                                      \
    char* Bb_ = Ah_ + 8192;                                                      \
    const int srow = lane & 15;                                                  \
    const int ksl = lane >> 4;                                                   \
    short8v ah[2], al[2];                                                        \
    _Pragma("unroll")                                                            \
    for (int fm = 0; fm < 2; ++fm) {                                             \
        int rr = wm * 32 + fm * 16 + srow;                                       \
        int off = rr * 64 + ((ksl ^ ((rr >> 1) & 3)) << 4);                      \
        ah[fm] = *(const short8v*)(Ah_ + off);                                   \
        al[fm] = *(const short8v*)(Al_ + off);                                   \
    }                                                                            \
    _Pragma("unroll")                                                            \
    for (int fn = 0; fn < 2; ++fn) {                                             \
        int rb = wn * 32 + fn * 16 + srow;                                       \
        int boff = rb * 64 + ((ksl ^ ((rb >> 1) & 3)) << 4);                     \
        short8v bfr = *(const short8v*)(Bb_ + boff);                             \
        short8v bfz = *(const short8v*)(Bb_ + 8192 + boff);                      \
        short8v bfn = *(const short8v*)(Bb_ + 16384 + boff);                     \
        _Pragma("unroll")                                                        \
        for (int fm = 0; fm < 2; ++fm) {                                         \
            acc[0][fn][fm] = __builtin_amdgcn_mfma_f32_16x16x32_bf16(ah[fm], bfr, acc[0][fn][fm], 0, 0, 0); \
            acc[0][fn][fm] = __builtin_amdgcn_mfma_f32_16x16x32_bf16(al[fm], bfr, acc[0][fn][fm], 0, 0, 0); \
            acc[1][fn][fm] = __builtin_amdgcn_mfma_f32_16x16x32_bf16(ah[fm], bfz, acc[1][fn][fm], 0, 0, 0); \
            acc[1][fn][fm] = __builtin_amdgcn_mfma_f32_16x16x32_bf16(al[fm], bfz, acc[1][fn][fm], 0, 0, 0); \
            acc[NSLOT][fn][fm] = __builtin_amdgcn_mfma_f32_16x16x32_bf16(ah[fm], bfn, acc[NSLOT][fn][fm], 0, 0, 0); \
            acc[NSLOT][fn][fm] = __builtin_amdgcn_mfma_f32_16x16x32_bf16(al[fm], bfn, acc[NSLOT][fn][fm], 0, 0, 0); \
        }                                                                        \
    }                                                                            \
} while (0)

__global__ __launch_bounds__(512) void k_gruf(
        const u16* __restrict__ act,   // [NB][KCAT]: r filled + h_cur
        const u16* __restrict__ Wc,    // [3*1024][KWC]
        const float* __restrict__ bih, const float* __restrict__ bhh,
        u16* __restrict__ actn) {      // h_new -> h-section
    __shared__ char lds[65536];        // 2 x (A_hi 4K + A_lo 4K + B 24K)
    const int t = threadIdx.x;
    const int lane = t & 63;
    const int wid = t >> 6;          // 0..7
    const int wm = wid >> 2;         // 0..1: 32-row band
    const int wn = wid & 3;          // 0..3: 32-col band per gate
    const int bid = blockIdx.x;
    const int xcd = bid & 7;
    const int slot = bid >> 3;       // 0..63
    const int m0 = (xcd * 8 + (slot & 7)) * 64;
    const int n0 = (slot >> 3) * 128;

    f32x4 acc[4][2][2];
    #pragma unroll
    for (int i = 0; i < 4; ++i)
        #pragma unroll
        for (int j = 0; j < 2; ++j)
            #pragma unroll
            for (int k = 0; k < 2; ++k) {
                f32x4 z = {0.f, 0.f, 0.f, 0.f};
                acc[i][j][k] = z;
            }

    auto stage = [&](int step, int buf) {   // 4 gl16 per thread
        char* Ah_ = lds + buf * 32768;
        char* Al_ = Ah_ + 4096;
        char* Bb_ = Ah_ + 8192;
        const int hiOff = (step < NSTEP_R) ? step * 32 : step * 32 + 1088;
        const int loOff = hiOff + ((step < NSTEP_R) ? 1088 : 1024);
        const int wOff = step * 32;
        {
            int rr = (wid & 3) * 16 + (lane >> 2);     // 0..63
            int kq = ((lane & 3) ^ ((rr >> 1) & 3)) << 3;
            if (wid < 4)
                gl16(act + (size_t)(m0 + rr) * KCAT + hiOff + kq, Ah_ + (wid & 3) * 1024);
            else
                gl16(act + (size_t)(m0 + rr) * KCAT + loOff + kq, Al_ + (wid & 3) * 1024);
        }
        #pragma unroll
        for (int j = 0; j < 3; ++j) {
            int cb = wid * 3 + j;              // 0..23
            int rbg = cb * 16 + (lane >> 2);   // 0..383
            int kq = ((lane & 3) ^ ((rbg >> 1) & 3)) << 3;
            gl16(Wc + (size_t)((rbg >> 7) * 1024 + n0 + (rbg & 127)) * KWC + wOff + kq,
                 Bb_ + cb * 1024);
        }
    };

    stage(0, 0);
    __syncthreads();
    int cur = 0;
    for (int step = 0; step < NSTEP_R; ++step) {       // r-part: n-gate -> i_n
        stage(step + 1, cur ^ 1);
        GRUF_STEP(2, cur);
        __syncthreads();
        cur ^= 1;
    }
    for (int step = NSTEP_R; step < NSTEPS; ++step) {  // h-part: n-gate -> h_n
        if (step + 1 < NSTEPS) stage(step + 1, cur ^ 1);
        GRUF_STEP(3, cur);
        __syncthreads();
        cur ^= 1;
    }

    #pragma unroll
    for (int fn = 0; fn < 2; ++fn) {
        const int jj = n0 + wn * 32 + fn * 16 + (lane & 15);
        const float bir = bih[jj],        bhr = bhh[jj];
        const float biz = bih[1024 + jj], bhz = bhh[1024 + jj];
        const float bin = bih[2048 + jj], bhn = bhh[2048 + jj];
        #pragma unroll
        for (int fm = 0; fm < 2; ++fm) {
            #pragma unroll
            for (int rg = 0; rg < 4; ++rg) {
                int m = m0 + wm * 32 + fm * 16 + (lane >> 4) * 4 + rg;
                float rz = acc[0][fn][fm][rg];
                float zz = acc[1][fn][fm][rg];
                float inn = acc[2][fn][fm][rg];
                float hnn = acc[3][fn][fm][rg];
                float rgate = 1.f / (1.f + expf(-(rz + bir + bhr)));
                float zgate = 1.f / (1.f + expf(-(zz + biz + bhz)));
                float ngate = tanhf(inn + bin + rgate * (hnn + bhn));
                size_t base = (size_t)m * KCAT + HOFF;
                float hv = b2f(act[base + jj]) + b2f(act[base + HIDD + jj]);
                float hnew = (1.f - zgate) * ngate + zgate * hv;
                u16 nh = f2b(hnew);
                actn[base + jj] = nh;
                actn[base + HIDD + jj] = f2b(hnew - b2f(nh));
            }
        }
    }
}

// out = h_new @ W_out^T + b_out; tile 64 x 128, grid (64,3), 2-buf 32KB.
__global__ __launch_bounds__(512) void k_outp(
        const u16* __restrict__ act, const u16* __restrict__ Wo,
        const float* __restrict__ bo, float* __restrict__ outb) {
    __shared__ char lds[32768];        // 2 x (A_hi 4K + A_lo 4K + B 8K)
    const int t = threadIdx.x;
    const int lane = t & 63;
    const int wid = t >> 6;
    const int wm = wid >> 2;           // 0..1
    const int wn = wid & 3;            // 0..3
    const int m0 = blockIdx.x * 64;
    const int n0 = blockIdx.y * 128;
    f32x4 acc[2][2];
    #pragma unroll
    for (int i = 0; i < 2; ++i)
        #pragma unroll
        for (int j = 0; j < 2; ++j) {
            f32x4 z = {0.f, 0.f, 0.f, 0.f};
            acc[i][j] = z;
        }

    auto stage = [&](int step, int buf) {   // 2 gl16 per thread
        char* Ah_ = lds + buf * 16384;
        char* Al_ = Ah_ + 4096;
        char* Bb_ = Ah_ + 8192;
        {
            int rr = (wid & 3) * 16 + (lane >> 2);     // 0..63
            int kq = ((lane & 3) ^ ((rr >> 1) & 3)) << 3;
            if (wid < 4)
                gl16(act + (size_t)(m0 + rr) * KCAT + HOFF + step * 32 + kq,
                     Ah_ + (wid & 3) * 1024);
            else
                gl16(act + (size_t)(m0 + rr) * KCAT + HOFF + HIDD + step * 32 + kq,
                     Al_ + (wid & 3) * 1024);
        }
        {
            int rb = wid * 16 + (lane >> 2);           // 0..127
            int kq = ((lane & 3) ^ ((rb >> 1) & 3)) << 3;
            gl16(Wo + (size_t)(n0 + rb) * KWO + step * 32 + kq, Bb_ + wid * 1024);
        }
    };

    stage(0, 0);
    __syncthreads();
    int cur = 0;
    for (int step = 0; step < 32; ++step) {
        if (step + 1 < 32) stage(step + 1, cur ^ 1);
        {
            char* Ah_ = lds + cur * 16384;
            char* Al_ = Ah_ + 4096;
            char* Bb_ = Ah_ + 8192;
            const int srow = lane & 15;
            const int ksl = lane >> 4;
            short8v ah[2], al[2];
            #pragma unroll
            for (int fm = 0; fm < 2; ++fm) {
                int rr = wm * 32 + fm * 16 + srow;
                int off = rr * 64 + ((ksl ^ ((rr >> 1) & 3)) << 4);
                ah[fm] = *(const short8v*)(Ah_ + off);
                al[fm] = *(const short8v*)(Al_ + off);
            }
            #pragma unroll
            for (int fn = 0; fn < 2; ++fn) {
                int rb = wn * 32 + fn * 16 + srow;
                int boff = rb * 64 + ((ksl ^ ((rb >> 1) & 3)) << 4);
                short8v bf = *(const short8v*)(Bb_ + boff);
                #pragma unroll
                for (int fm = 0; fm < 2; ++fm) {
                    acc[fn][fm] = __builtin_amdgcn_mfma_f32_16x16x32_bf16(ah[fm], bf, acc[fn][fm], 0, 0, 0);
                    acc[fn][fm] = __builtin_amdgcn_mfma_f32_16x16x32_bf16(al[fm], bf, acc[fn][fm], 0, 0, 0);
                }
            }
        }
        __syncthreads();
        cur ^= 1;
    }
    #pragma unroll
    for (int fn = 0; fn < 2; ++fn) {
        int n = n0 + wn * 32 + fn * 16 + (lane & 15);
        if (n < NOUTD) {
            float bb = bo[n];
            #pragma unroll
            for (int fm = 0; fm < 2; ++fm) {
                #pragma unroll
                for (int rg = 0; rg < 4; ++rg) {
                    int m = m0 + wm * 32 + fm * 16 + (lane >> 4) * 4 + rg;
                    outb[(size_t)m * NOUTP + n] = acc[fn][fm][rg] + bb;
                }
            }
        }
    }
}

// ---------------------------------------------------------------------------
extern "C" void kernel_launch(void* const* d_in, const int* in_sizes, int n_in,
                              void* d_out, int out_size, void* d_ws, size_t ws_size,
                              hipStream_t stream) {
    const float* lamda_init = (const float*)d_in[0];
    // d_in[1] = s_init (unused: multiplied by 0 in reference)
    const float* h0    = (const float*)d_in[2];
    const float* H     = (const float*)d_in[3];
    const float* g     = (const float*)d_in[4];
    const float* C     = (const float*)d_in[5];
    const float* c     = (const float*)d_in[6];
    const float* W_ih  = (const float*)d_in[7];
    const float* b_ih  = (const float*)d_in[8];
    const float* W_hh  = (const float*)d_in[9];
    const float* b_hh  = (const float*)d_in[10];
    const float* W_out = (const float*)d_in[11];
    const float* b_out = (const float*)d_in[12];

    float* out    = (float*)d_out;
    float* xi_out = out;                       // [B,120]
    float* primal = out + (size_t)NB*NV;       // [8,B]
    float* fixedo = primal + (size_t)NITER*NB; // [8,B]
    float* qpres  = fixedo + (size_t)NITER*NB; // [8,B]

    char* wp = (char*)d_ws;
    auto alloc = [&](size_t bytes) {
        void* p = (void*)wp;
        wp += (bytes + 255) & ~(size_t)255;
        return p;
    };
    float* Amat  = (float*)alloc(NV*NV*4);
    float* A0m   = (float*)alloc(NV*NV*4);
    float* Qinv  = (float*)alloc(NV*NV*4);
    float* Qinv0 = (float*)alloc(NV*NV*4);
    float* CTg   = (float*)alloc((size_t)NV*NCN*4);
    float* s0v   = (float*)alloc(NCN*4);
    float* sbuf  = (float*)alloc((size_t)NB*NCN*4);
    float* snew  = (float*)alloc((size_t)NB*NCN*4);
    float* lam   = (float*)alloc((size_t)NB*NV*4);
    float* lamn  = (float*)alloc((size_t)NB*NV*4);
    float* xib   = (float*)alloc((size_t)NB*NV*4);
    float* Yb    = (float*)alloc((size_t)NB*NV*4);
    float* wb    = (float*)alloc(NB*4);
    float* outb  = (float*)alloc((size_t)NB*NOUTP*4);
    u16* actA    = (u16*)alloc((size_t)NB*KCAT*2);
    u16* actB    = (u16*)alloc((size_t)NB*KCAT*2);
    u16* Wcat    = (u16*)alloc((size_t)3072*KWC*2);
    u16* Wopk    = (u16*)alloc((size_t)NOUTP*KWO*2);
    float* Gpart = (float*)alloc((size_t)NPART*NV*NV*4);
    float* vpart = (float*)alloc((size_t)NPART*NV*4);
    float* Spart = (float*)alloc(NPART*4);
    double* Gfin  = (double*)alloc(NV*NV*8);
    double* vfin  = (double*)alloc(NV*8);
    double* Sfin  = (double*)alloc(8);

    k_buildA<<<dim3(NV, 2), dim3(128), 0, stream>>>(H, C, Amat, A0m);
    k_buildCT<<<dim3(NV), dim3(256), 0, stream>>>(C, CTg);
    k_invert<<<dim3(2), dim3(1024), 0, stream>>>(Amat, A0m, Qinv, Qinv0);
    k_s0<<<dim3(1), dim3(256), 0, stream>>>(Qinv0, g, C, c, s0v);
    k_init<<<dim3(NB/8), dim3(256), 0, stream>>>(s0v, lamda_init, sbuf, lam);
    k_packWcat<<<dim3(3072), dim3(256), 0, stream>>>(W_ih, W_hh, Wcat);
    k_packWo<<<dim3(NOUTP), dim3(256), 0, stream>>>(W_out, Wopk);
    k_packH<<<dim3(NB), dim3(256), 0, stream>>>(h0, actA);

    u16* hc = actA;
    u16* hn2 = actB;
    for (int it = 0; it < NITER; ++it) {
        k_xiproj<<<dim3(NB/XB), dim3(512), 0, stream>>>(sbuf, lam, C, CTg, c, g, Qinv, H,
                                                        xib, Yb, wb, snew, lamn, hc,
                                                        primal + (size_t)it*NB);
        k_qp_part<<<dim3(NPART), dim3(256), 0, stream>>>(xib, wb, Gpart, vpart, Spart);
        k_qp_red<<<dim3((NV*NV + 255)/256), dim3(256), 0, stream>>>(Gpart, vpart, Spart, Gfin, vfin, Sfin);
        k_gruf<<<dim3(512), dim3(512), 0, stream>>>(hc, Wcat, b_ih, b_hh, hn2);
        k_outp<<<dim3(64, 3), dim3(512), 0, stream>>>(hn2, Wopk, b_out, outb);
        k_tail<<<dim3(NB/16), dim3(256), 0, stream>>>(Yb, Gfin, vfin, Sfin,
                                                      qpres + (size_t)it*NB,
                                                      snew, lamn, outb, sbuf, lam,
                                                      fixedo + (size_t)it*NB);
        u16* tmp = hc; hc = hn2; hn2 = tmp;
    }
    hipMemcpyAsync(xi_out, xib, (size_t)NB*NV*sizeof(float), hipMemcpyDeviceToDevice, stream);
}

// Round 17
// 2092.761 us; speedup vs baseline: 1.1443x; 1.0359x over previous
//
#include <hip/hip_runtime.h>
#include <hip/hip_bf16.h>
#include <math.h>

// Problem constants (match reference)
#define NB    4096   // num_batch
#define NV    120    // NVAR
#define NCN   240    // num constraints
#define HIDD  1024   // GRU hidden
#define RINN  1080   // GRU input dim
#define NOUTD 360    // NC+NVAR
#define NOUTP 384    // padded out cols
#define NITER 8
#define REGEPS 1e-4f
#define NPART 128    // Gram partial blocks (32 batches each), FLOAT partials

// 2-term split: activations [hi|lo] (exact), weights stored ONCE (hi).
// GEMMs consume BOTH a_hi and a_lo (r14 ablation: dropping a_lo regressed).
// act row: [r_hi 1088 | r_lo 1088 | h_hi 1024 | h_lo 1024] = 4224
// Wcat row: [Wih_hi 1088 | Whh_hi 1024] = 2112 (B-reuse pairing)
#define KCAT 4224
#define HOFF 2176    // h section start within an act row
#define KWC  2112    // Wcat K
#define KWO  1024    // W_out packed K
#define NSTEP_R 34   // r-section 32-wide K-steps (1088/32)
#define NSTEPS  66   // total (2112/32)

typedef unsigned short u16;
typedef __attribute__((ext_vector_type(8))) short short8v;
typedef __attribute__((ext_vector_type(4))) float f32x4;

__device__ inline u16 f2b(float x) {
    __hip_bfloat16 h = __float2bfloat16(x);
    return __builtin_bit_cast(u16, h);
}
__device__ inline float b2f(u16 u) {
    __hip_bfloat16 h = __builtin_bit_cast(__hip_bfloat16, u);
    return __bfloat162float(h);
}

// async global -> LDS, 16B per lane (wave-uniform LDS base + lane*16)
__device__ inline void gl16(const void* g, void* l) {
    __builtin_amdgcn_global_load_lds(
        (__attribute__((address_space(1))) void*)(void*)g,
        (__attribute__((address_space(3))) void*)l, 16, 0, 0);
}

// ---------------------------------------------------------------------------
// Build A = H + C^T C + REG*I (which==0) and A0 = H + REG*I (which==1)
__global__ void k_buildA(const float* __restrict__ H, const float* __restrict__ C,
                         float* __restrict__ A, float* __restrict__ A0) {
    int i = blockIdx.x;
    int which = blockIdx.y;
    for (int j = threadIdx.x; j < NV; j += blockDim.x) {
        float v = H[i*NV + j] + (i == j ? REGEPS : 0.f);
        if (which == 0) {
            float acc = 0.f;
            for (int k = 0; k < NCN; ++k) acc += C[k*NV + i] * C[k*NV + j];
            A[i*NV + j] = v + acc;   // RHO = 1
        } else {
            A0[i*NV + j] = v;
        }
    }
}

// CT[j][k] = C[k][j]
__global__ void k_buildCT(const float* __restrict__ C, float* __restrict__ CT) {
    int j = blockIdx.x;   // 0..119
    for (int k = threadIdx.x; k < NCN; k += 256)
        CT[(size_t)j * NCN + k] = C[(size_t)k * NV + j];
}

// Row-major 4x4 inverse via 2x2-subdeterminant adjugate (ILP-friendly).
__device__ inline void inv4x4(const float* m, float* inv) {
    float s0 = m[0]*m[5] - m[1]*m[4];
    float s1 = m[0]*m[6] - m[2]*m[4];
    float s2 = m[0]*m[7] - m[3]*m[4];
    float s3 = m[1]*m[6] - m[2]*m[5];
    float s4 = m[1]*m[7] - m[3]*m[5];
    float s5 = m[2]*m[7] - m[3]*m[6];
    float c5 = m[10]*m[15] - m[11]*m[14];
    float c4 = m[9]*m[15] - m[11]*m[13];
    float c3 = m[9]*m[14] - m[10]*m[13];
    float c2 = m[8]*m[15] - m[11]*m[12];
    float c1 = m[8]*m[14] - m[10]*m[12];
    float c0 = m[8]*m[13] - m[9]*m[12];
    float det = s0*c5 - s1*c4 + s2*c3 + s3*c2 - s4*c1 + s5*c0;
    float id = 1.0f / det;
    inv[0]  = ( m[5]*c5 - m[6]*c4 + m[7]*c3) * id;
    inv[1]  = (-m[1]*c5 + m[2]*c4 - m[3]*c3) * id;
    inv[2]  = ( m[13]*s5 - m[14]*s4 + m[15]*s3) * id;
    inv[3]  = (-m[9]*s5 + m[10]*s4 - m[11]*s3) * id;
    inv[4]  = (-m[4]*c5 + m[6]*c2 - m[7]*c1) * id;
    inv[5]  = ( m[0]*c5 - m[2]*c2 + m[3]*c1) * id;
    inv[6]  = (-m[12]*s5 + m[14]*s2 - m[15]*s1) * id;
    inv[7]  = ( m[8]*s5 - m[10]*s2 + m[11]*s1) * id;
    inv[8]  = ( m[4]*c4 - m[5]*c2 + m[7]*c0) * id;
    inv[9]  = (-m[0]*c4 + m[1]*c2 - m[3]*c0) * id;
    inv[10] = ( m[12]*s4 - m[13]*s2 + m[15]*s0) * id;
    inv[11] = (-m[8]*s4 + m[9]*s2 - m[11]*s0) * id;
    inv[12] = (-m[4]*c3 + m[5]*c1 - m[6]*c0) * id;
    inv[13] = ( m[0]*c3 - m[1]*c1 + m[2]*c0) * id;
    inv[14] = (-m[12]*s3 + m[13]*s1 - m[14]*s0) * id;
    inv[15] = ( m[8]*s3 - m[9]*s1 + m[10]*s0) * id;
}

// Blocked rank-4 Gauss-Jordan, phase-split. 2 barriers/chunk, 30 chunks.
__global__ __launch_bounds__(1024) void k_invert(const float* __restrict__ Ain,
                                                 const float* __restrict__ A0in,
                                                 float* __restrict__ Qi,
                                                 float* __restrict__ Qi0) {
    __shared__ float M[NV][132];
    __shared__ float Rl[4][132];
    __shared__ float Bl[16];
    const float* src = (blockIdx.x == 0) ? Ain : A0in;
    float* dst = (blockIdx.x == 0) ? Qi : Qi0;
    const int t = threadIdx.x;
    for (int idx = t; idx < NV*132; idx += 1024) {
        int i = idx / 132, j = idx - i*132;
        M[i][j] = (j < NV) ? src[i*NV + j] : 0.f;
    }
    __syncthreads();
    const int ty = t >> 5;        // 0..31 row owner (4 rows each)
    const int g4 = (t & 31) * 4;  // col group 0..124
    for (int kk = 0; kk < NV; kk += 4) {
        if (ty == 0) {
            float a[16], b[16];
            #pragma unroll
            for (int p = 0; p < 4; ++p) {
                float4 v = *(const float4*)&M[kk + p][kk];
                a[p*4+0] = v.x; a[p*4+1] = v.y; a[p*4+2] = v.z; a[p*4+3] = v.w;
            }
            inv4x4(a, b);
            float4 m0v = *(const float4*)&M[kk+0][g4];
            float4 m1v = *(const float4*)&M[kk+1][g4];
            float4 m2v = *(const float4*)&M[kk+2][g4];
            float4 m3v = *(const float4*)&M[kk+3][g4];
            #pragma unroll
            for (int p = 0; p < 4; ++p) {
                float4 r;
                r.x = b[p*4+0]*m0v.x + b[p*4+1]*m1v.x + b[p*4+2]*m2v.x + b[p*4+3]*m3v.x;
                r.y = b[p*4+0]*m0v.y + b[p*4+1]*m1v.y + b[p*4+2]*m2v.y + b[p*4+3]*m3v.y;
                r.z = b[p*4+0]*m0v.z + b[p*4+1]*m1v.z + b[p*4+2]*m2v.z + b[p*4+3]*m3v.z;
                r.w = b[p*4+0]*m0v.w + b[p*4+1]*m1v.w + b[p*4+2]*m2v.w + b[p*4+3]*m3v.w;
                *(float4*)&Rl[p][g4] = r;
            }
            if (t < 16) Bl[t] = b[t];
        }
        float4 F[4];
        #pragma unroll
        for (int q = 0; q < 4; ++q) {
            int i = ty + 32*q;
            F[q] = (i < NV) ? *(const float4*)&M[i][kk] : float4{0.f,0.f,0.f,0.f};
        }
        __syncthreads();
        #pragma unroll
        for (int q = 0; q < 4; ++q) {
            int i = ty + 32*q;
            if (i < NV) {
                int dp = i - kk;
                bool ispiv = (dp >= 0) && (dp < 4);
                float4 v;
                if (g4 == kk) {
                    if (ispiv) {
                        v = *(const float4*)&Bl[dp*4];
                    } else {
                        v.x = -(F[q].x*Bl[0] + F[q].y*Bl[4] + F[q].z*Bl[8]  + F[q].w*Bl[12]);
                        v.y = -(F[q].x*Bl[1] + F[q].y*Bl[5] + F[q].z*Bl[9]  + F[q].w*Bl[13]);
                        v.z = -(F[q].x*Bl[2] + F[q].y*Bl[6] + F[q].z*Bl[10] + F[q].w*Bl[14]);
                        v.w = -(F[q].x*Bl[3] + F[q].y*Bl[7] + F[q].z*Bl[11] + F[q].w*Bl[15]);
                    }
                } else if (ispiv) {
                    v = *(const float4*)&Rl[dp][g4];
                } else {
                    float4 r0 = *(const float4*)&Rl[0][g4];
                    float4 r1 = *(const float4*)&Rl[1][g4];
                    float4 r2 = *(const float4*)&Rl[2][g4];
                    float4 r3 = *(const float4*)&Rl[3][g4];
                    v = *(const float4*)&M[i][g4];
                    v.x -= F[q].x*r0.x + F[q].y*r1.x + F[q].z*r2.x + F[q].w*r3.x;
                    v.y -= F[q].x*r0.y + F[q].y*r1.y + F[q].z*r2.y + F[q].w*r3.y;
                    v.z -= F[q].x*r0.z + F[q].y*r1.z + F[q].z*r2.z + F[q].w*r3.z;
                    v.w -= F[q].x*r0.w + F[q].y*r1.w + F[q].z*r2.w + F[q].w*r3.w;
                }
                *(float4*)&M[i][g4] = v;
            }
        }
        __syncthreads();
    }
    for (int idx = t; idx < NV*NV; idx += 1024) {
        int i = idx / NV, j = idx - i*NV;
        dst[idx] = M[i][j];
    }
}

// xi0 = (-g) @ Qinv0^T ; s0 = max(0, c - C xi0)   (batch-constant vectors)
__global__ void k_s0(const float* __restrict__ Qi0, const float* __restrict__ g,
                     const float* __restrict__ C, const float* __restrict__ c,
                     float* __restrict__ s0v) {
    __shared__ float xi0[NV];
    int t = threadIdx.x;
    if (t < NV) {
        float a = 0.f;
        for (int j = 0; j < NV; ++j) a += Qi0[t*NV + j] * g[j];
        xi0[t] = -a;
    }
    __syncthreads();
    if (t < NCN) {
        float a = 0.f;
        for (int j = 0; j < NV; ++j) a += C[t*NV + j] * xi0[j];
        s0v[t] = fmaxf(0.f, c[t] - a);
    }
}

// Initialize state: s = broadcast(s0), lam = lamda_init
__global__ void k_init(const float* __restrict__ s0v, const float* __restrict__ lam0,
                       float* __restrict__ s, float* __restrict__ lam) {
    int b0 = blockIdx.x * 8;
    int t = threadIdx.x;
    for (int idx = t; idx < 8*NCN; idx += 256) {
        int m = idx / NCN, k = idx % NCN;
        s[(size_t)(b0 + m)*NCN + k] = s0v[k];
    }
    for (int idx = t; idx < 8*NV; idx += 256) lam[(size_t)b0*NV + idx] = lam0[(size_t)b0*NV + idx];
}

// Pack h0 into act buffer h-section: [h_hi | h_lo]
__global__ void k_packH(const float* __restrict__ h0, u16* __restrict__ act) {
    int n = blockIdx.x;
    size_t base = (size_t)n * KCAT + HOFF;
    for (int k = threadIdx.x; k < HIDD; k += 256) {
        float x = h0[(size_t)n * HIDD + k];
        u16 hi = f2b(x);
        act[base + k] = hi;
        act[base + HIDD + k] = f2b(x - b2f(hi));
    }
}

// Pack Wih+Whh (hi only, once): [Wih_hi 1088 | Whh_hi 1024]
__global__ void k_packWcat(const float* __restrict__ Wih, const float* __restrict__ Whh,
                           u16* __restrict__ Wc) {
    int n = blockIdx.x;   // 0..3071
    size_t base = (size_t)n * KWC;
    for (int k = threadIdx.x; k < 1088; k += 256)
        Wc[base + k] = f2b(k < RINN ? Wih[(size_t)n * RINN + k] : 0.f);
    for (int k = threadIdx.x; k < HIDD; k += 256)
        Wc[base + 1088 + k] = f2b(Whh[(size_t)n * HIDD + k]);
}

// Pack W_out (hi only): [NOUTP rows][1024]
__global__ void k_packWo(const float* __restrict__ src, u16* __restrict__ dst) {
    int n = blockIdx.x;
    size_t row = (size_t)n * KWO;
    for (int k = threadIdx.x; k < KWO; k += 256)
        dst[row + k] = f2b(n < NOUTD ? src[(size_t)n * HIDD + k] : 0.f);
}

__device__ inline void write2(u16* __restrict__ act, size_t base, int pos, float x) {
    u16 hi = f2b(x);
    u16 lo = f2b(x - b2f(hi));
    act[base + pos] = hi;
    act[base + 1088 + pos] = lo;
}

__device__ inline float hadd4(float4 v) { return (v.x + v.y) + (v.z + v.w); }

// ---------------------------------------------------------------------------
// Fused: xi solve + projection + GRU-input pack. XB=16 batches/block,
// 256 blocks, 1024 THREADS (r16 ran 512: phases were 480-active with phase 5
// double-passed and Msh stages 62 iterations; 1024 threads halves stage
// iteration count and makes phase 5 single-pass -> shorter serial chain).
// bd overlays resl (disjoint live ranges). LDS ~157.4KB -> 1 block/CU.
#define XB 16
__global__ __launch_bounds__(1024) void k_xiproj(
        const float* __restrict__ s, const float* __restrict__ lam,
        const float* __restrict__ Cg, const float* __restrict__ CTg,
        const float* __restrict__ c,
        const float* __restrict__ g, const float* __restrict__ Qi,
        const float* __restrict__ Hg,
        float* __restrict__ xi, float* __restrict__ Y, float* __restrict__ wv,
        float* __restrict__ snew, float* __restrict__ lamn,
        u16* __restrict__ act, float* __restrict__ primal) {
    __shared__ float Msh[31680];      // C/QH: [240][132]; CT: [120][244]
    __shared__ float resl[XB][NCN];   // phase5/6 residuals; ALSO bd in phase2
    __shared__ float ul[XB][NV];
    __shared__ float xl[XB][NV];
    const int b0 = blockIdx.x * XB;
    const int t = threadIdx.x;
    #define bd resl

    // stage CT + bd
    for (int idx = t; idx < XB*NCN; idx += 1024) {
        int m = idx / NCN, k = idx - m*NCN;
        bd[m][k] = c[k] - s[(size_t)(b0 + m)*NCN + k];
    }
    for (int idx = t; idx < NV*NCN; idx += 1024) {
        int i = idx / NCN, k = idx - i*NCN;
        Msh[i*244 + k] = CTg[idx];
    }
    __syncthreads();
    // phase 2: ul_j = lam_j - g_j + sum_k bd_k CT[j][k]
    if (t < 480) {
        int m = t / 30, jb = t - (t / 30) * 30;
        float4 a0 = {0,0,0,0}, a1 = {0,0,0,0}, a2 = {0,0,0,0}, a3 = {0,0,0,0};
        for (int kg = 0; kg < 60; ++kg) {
            float4 b4 = *(const float4*)&bd[m][kg*4];
            float4 c0 = *(const float4*)&Msh[(jb     ) * 244 + kg*4];
            float4 c1 = *(const float4*)&Msh[(jb + 30) * 244 + kg*4];
            float4 c2 = *(const float4*)&Msh[(jb + 60) * 244 + kg*4];
            float4 c3 = *(const float4*)&Msh[(jb + 90) * 244 + kg*4];
            a0.x += b4.x*c0.x; a0.y += b4.y*c0.y; a0.z += b4.z*c0.z; a0.w += b4.w*c0.w;
            a1.x += b4.x*c1.x; a1.y += b4.y*c1.y; a1.z += b4.z*c1.z; a1.w += b4.w*c1.w;
            a2.x += b4.x*c2.x; a2.y += b4.y*c2.y; a2.z += b4.z*c2.z; a2.w += b4.w*c2.w;
            a3.x += b4.x*c3.x; a3.y += b4.y*c3.y; a3.z += b4.z*c3.z; a3.w += b4.w*c3.w;
        }
        #pragma unroll
        for (int p = 0; p < 4; ++p) {
            int j = jb + 30*p;
            float h = (p == 0) ? hadd4(a0) : (p == 1) ? hadd4(a1) : (p == 2) ? hadd4(a2) : hadd4(a3);
            ul[m][j] = lam[(size_t)(b0 + m)*NV + j] - g[j] + h;
        }
    }
    __syncthreads();
    // stage Qinv (rows 0..119) + H (rows 120..239), stride 132
    for (int idx = t; idx < NV*NV; idx += 1024) {
        int i = idx / NV, j = idx - i*NV;
        Msh[i*132 + j] = Qi[idx];
        Msh[(120 + i)*132 + j] = Hg[idx];
    }
    __syncthreads();
    // phase 3: xi_i = sum_j Qinv[i][j] ul_j
    if (t < 480) {
        int m = t / 30, ib = t - (t / 30) * 30;
        float4 a0 = {0,0,0,0}, a1 = {0,0,0,0}, a2 = {0,0,0,0}, a3 = {0,0,0,0};
        for (int jg = 0; jg < 30; ++jg) {
            float4 u4 = *(const float4*)&ul[m][jg*4];
            float4 q0 = *(const float4*)&Msh[(ib     ) * 132 + jg*4];
            float4 q1 = *(const float4*)&Msh[(ib + 30) * 132 + jg*4];
            float4 q2 = *(const float4*)&Msh[(ib + 60) * 132 + jg*4];
            float4 q3 = *(const float4*)&Msh[(ib + 90) * 132 + jg*4];
            a0.x += u4.x*q0.x; a0.y += u4.y*q0.y; a0.z += u4.z*q0.z; a0.w += u4.w*q0.w;
            a1.x += u4.x*q1.x; a1.y += u4.y*q1.y; a1.z += u4.z*q1.z; a1.w += u4.w*q1.w;
            a2.x += u4.x*q2.x; a2.y += u4.y*q2.y; a2.z += u4.z*q2.z; a2.w += u4.w*q2.w;
            a3.x += u4.x*q3.x; a3.y += u4.y*q3.y; a3.z += u4.z*q3.z; a3.w += u4.w*q3.w;
        }
        #pragma unroll
        for (int p = 0; p < 4; ++p) {
            int i = ib + 30*p;
            float a = (p == 0) ? hadd4(a0) : (p == 1) ? hadd4(a1) : (p == 2) ? hadd4(a2) : hadd4(a3);
            xl[m][i] = a;
            xi[(size_t)(b0 + m)*NV + i] = a;
        }
    }
    __syncthreads();
    // phase 4: Y_i = sum_j xl_j H[i][j]; wv = xl . g
    if (t < 480) {
        int m = t / 30, ib = t - (t / 30) * 30;
        float4 a0 = {0,0,0,0}, a1 = {0,0,0,0}, a2 = {0,0,0,0}, a3 = {0,0,0,0};
        for (int jg = 0; jg < 30; ++jg) {
            float4 x4 = *(const float4*)&xl[m][jg*4];
            float4 h0 = *(const float4*)&Msh[(120 + ib     ) * 132 + jg*4];
            float4 h1 = *(const float4*)&Msh[(120 + ib + 30) * 132 + jg*4];
            float4 h2 = *(const float4*)&Msh[(120 + ib + 60) * 132 + jg*4];
            float4 h3 = *(const float4*)&Msh[(120 + ib + 90) * 132 + jg*4];
            a0.x += x4.x*h0.x; a0.y += x4.y*h0.y; a0.z += x4.z*h0.z; a0.w += x4.w*h0.w;
            a1.x += x4.x*h1.x; a1.y += x4.y*h1.y; a1.z += x4.z*h1.z; a1.w += x4.w*h1.w;
            a2.x += x4.x*h2.x; a2.y += x4.y*h2.y; a2.z += x4.z*h2.z; a2.w += x4.w*h2.w;
            a3.x += x4.x*h3.x; a3.y += x4.y*h3.y; a3.z += x4.z*h3.z; a3.w += x4.w*h3.w;
        }
        #pragma unroll
        for (int p = 0; p < 4; ++p) {
            int i = ib + 30*p;
            float a = (p == 0) ? hadd4(a0) : (p == 1) ? hadd4(a1) : (p == 2) ? hadd4(a2) : hadd4(a3);
            Y[(size_t)(b0 + m)*NV + i] = a;
        }
    }
    if (t >= 480 && t < 480 + XB) {
        int m = t - 480;
        float a = 0.f;
        for (int j = 0; j < NV; ++j) a += xl[m][j] * g[j];
        wv[b0 + m] = a;
    }
    __syncthreads();
    // stage C (rows 0..239, stride 132)
    for (int idx = t; idx < NCN*NV; idx += 1024) {
        int k = idx / NV, j = idx - k*NV;
        Msh[k*132 + j] = Cg[idx];
    }
    __syncthreads();
    // phase 5: Axi_k -> s_new, res, r-pack(s). 960 slots, single pass.
    if (t < 960) {
        int m = t / 60, kb = t - (t / 60) * 60;
        float4 a0 = {0,0,0,0}, a1 = {0,0,0,0}, a2 = {0,0,0,0}, a3 = {0,0,0,0};
        for (int jg = 0; jg < 30; ++jg) {
            float4 x4 = *(const float4*)&xl[m][jg*4];
            float4 c0 = *(const float4*)&Msh[(kb      ) * 132 + jg*4];
            float4 c1 = *(const float4*)&Msh[(kb + 60 ) * 132 + jg*4];
            float4 c2 = *(const float4*)&Msh[(kb + 120) * 132 + jg*4];
            float4 c3 = *(const float4*)&Msh[(kb + 180) * 132 + jg*4];
            a0.x += x4.x*c0.x; a0.y += x4.y*c0.y; a0.z += x4.z*c0.z; a0.w += x4.w*c0.w;
            a1.x += x4.x*c1.x; a1.y += x4.y*c1.y; a1.z += x4.z*c1.z; a1.w += x4.w*c1.w;
            a2.x += x4.x*c2.x; a2.y += x4.y*c2.y; a2.z += x4.z*c2.z; a2.w += x4.w*c2.w;
            a3.x += x4.x*c3.x; a3.y += x4.y*c3.y; a3.z += x4.z*c3.z; a3.w += x4.w*c3.w;
        }
        #pragma unroll
        for (int p = 0; p < 4; ++p) {
            int k = kb + 60*p;
            float a = (p == 0) ? hadd4(a0) : (p == 1) ? hadd4(a1) : (p == 2) ? hadd4(a2) : hadd4(a3);
            float sn = fmaxf(0.f, c[k] - a);
            float rv = a - c[k] + sn;
            resl[m][k] = rv;
            int b = b0 + m;
            snew[(size_t)b*NCN + k] = sn;
            float so = s[(size_t)b*NCN + k];
            size_t base = (size_t)b * KCAT;
            write2(act, base, k, so);
            write2(act, base, 360 + k, sn);
            write2(act, base, 720 + k, sn - so);
        }
    }
    __syncthreads();
    // restage CT + primal
    if (t < XB) {
        float a = 0.f;
        for (int k = 0; k < NCN; ++k) a += resl[t][k] * resl[t][k];
        primal[b0 + t] = sqrtf(a);
    }
    for (int idx = t; idx < NV*NCN; idx += 1024) {
        int i = idx / NCN, k = idx - i*NCN;
        Msh[i*244 + k] = CTg[idx];
    }
    __syncthreads();
    // phase 6: lam update + r-pack(lam)
    if (t < 480) {
        int m = t / 30, ib = t - (t / 30) * 30;
        float4 a0 = {0,0,0,0}, a1 = {0,0,0,0}, a2 = {0,0,0,0}, a3 = {0,0,0,0};
        for (int kg = 0; kg < 60; ++kg) {
            float4 r4 = *(const float4*)&resl[m][kg*4];
            float4 c0 = *(const float4*)&Msh[(ib     ) * 244 + kg*4];
            float4 c1 = *(const float4*)&Msh[(ib + 30) * 244 + kg*4];
            float4 c2 = *(const float4*)&Msh[(ib + 60) * 244 + kg*4];
            float4 c3 = *(const float4*)&Msh[(ib + 90) * 244 + kg*4];
            a0.x += r4.x*c0.x; a0.y += r4.y*c0.y; a0.z += r4.z*c0.z; a0.w += r4.w*c0.w;
            a1.x += r4.x*c1.x; a1.y += r4.y*c1.y; a1.z += r4.z*c1.z; a1.w += r4.w*c1.w;
            a2.x += r4.x*c2.x; a2.y += r4.y*c2.y; a2.z += r4.z*c2.z; a2.w += r4.w*c2.w;
            a3.x += r4.x*c3.x; a3.y += r4.y*c3.y; a3.z += r4.z*c3.z; a3.w += r4.w*c3.w;
        }
        #pragma unroll
        for (int p = 0; p < 4; ++p) {
            int i = ib + 30*p;
            float a = (p == 0) ? hadd4(a0) : (p == 1) ? hadd4(a1) : (p == 2) ? hadd4(a2) : hadd4(a3);
            int b = b0 + m;
            float lo = lam[(size_t)b*NV + i];
            float ln = lo - a;
            lamn[(size_t)b*NV + i] = ln;
            size_t base = (size_t)b * KCAT;
            write2(act, base, 240 + i, lo);
            write2(act, base, 600 + i, ln);
            write2(act, base, 960 + i, ln - lo);
        }
    }
    for (int idx = t; idx < XB*8; idx += 1024) {
        int m = idx >> 3, k = 1080 + (idx & 7);
        size_t base = (size_t)(b0 + m) * KCAT;
        act[base + k] = 0;
        act[base + 1088 + k] = 0;
    }
    #undef bd
}

// Partial Gram (FLOAT partials): 128 blocks x 32 batches.
__global__ __launch_bounds__(256) void k_qp_part(const float* __restrict__ xi, const float* __restrict__ wv,
                         float* __restrict__ Gp, float* __restrict__ vp, float* __restrict__ Sp) {
    __shared__ float xl[32][NV];
    __shared__ float wl[32];
    int p = blockIdx.x;
    int b0 = p * 32;
    int t = threadIdx.x;
    for (int idx = t; idx < 32*NV; idx += 256) xl[idx/NV][idx%NV] = xi[(size_t)b0*NV + idx];
    if (t < 32) wl[t] = wv[b0 + t];
    __syncthreads();
    for (int idx = t; idx < NV*NV; idx += 256) {
        int i = idx / NV, j = idx % NV;
        float a = 0.f;
        #pragma unroll
        for (int m = 0; m < 32; ++m) a += xl[m][i] * xl[m][j];
        Gp[(size_t)p*NV*NV + idx] = a;
    }
    if (t < NV) {
        float a = 0.f;
        #pragma unroll
        for (int m = 0; m < 32; ++m) a += wl[m] * xl[m][t];
        vp[(size_t)p*NV + t] = a;
    }
    if (t == 0) {
        float a = 0.f;
        #pragma unroll
        for (int m = 0; m < 32; ++m) a += wl[m] * wl[m];
        Sp[p] = a;
    }
}

__global__ void k_qp_red(const float* __restrict__ Gp, const float* __restrict__ vp,
                         const float* __restrict__ Sp,
                         double* __restrict__ G, double* __restrict__ v, double* __restrict__ S) {
    int idx = blockIdx.x * 256 + threadIdx.x;
    if (idx < NV*NV) {
        double a = 0.0;
        for (int p = 0; p < NPART; ++p) a += (double)Gp[(size_t)p*NV*NV + idx];
        G[idx] = a;
    }
    if (idx < NV) {
        double a = 0.0;
        for (int p = 0; p < NPART; ++p) a += (double)vp[(size_t)p*NV + idx];
        v[idx] = a;
    }
    if (idx == 0) {
        double a = 0.0;
        for (int p = 0; p < NPART; ++p) a += (double)Sp[p];
        S[0] = a;
    }
}

// ---------------------------------------------------------------------------
// Merged tail: qp_norm AND fin. 16 batches/block, grid 256.
__global__ __launch_bounds__(256) void k_tail(
        const float* __restrict__ Yb, const double* __restrict__ G,
        const double* __restrict__ v, const double* __restrict__ S,
        float* __restrict__ qp,
        const float* __restrict__ snew, const float* __restrict__ lamn,
        const float* __restrict__ outb,
        float* __restrict__ s, float* __restrict__ lam,
        float* __restrict__ fx) {
    __shared__ float Yl[16][NV];
    __shared__ double tl[16][NV];
    __shared__ float redS[16][17];
    __shared__ float redL[16][17];
    int b0 = blockIdx.x * 16;
    int t = threadIdx.x;
    for (int idx = t; idx < 16*NV; idx += 256) Yl[idx/NV][idx%NV] = Yb[(size_t)b0*NV + idx];
    __syncthreads();
    for (int idx = t; idx < 16*NV; idx += 256) {
        int m = idx / NV, i = idx % NV;
        double a = 0.0;
        for (int j = 0; j < NV; ++j) a += G[j*NV + i] * (double)Yl[m][j];  // G symmetric
        tl[m][i] = a;
    }
    __syncthreads();
    if (t < 16) {
        double a = 0.0, bv = 0.0;
        for (int i = 0; i < NV; ++i) { a += (double)Yl[t][i] * tl[t][i]; bv += (double)Yl[t][i] * v[i]; }
        double q = 0.25 * a + bv + S[0];
        qp[b0 + t] = (float)sqrt(q > 0.0 ? q : 0.0);
    }
    int tm = t / 16;
    int tk = t % 16;
    int b = b0 + tm;
    float ds2 = 0.f, dl2 = 0.f;
    for (int k = tk; k < NCN; k += 16) {
        float o = outb[(size_t)b*NOUTP + k];
        float sf = fmaxf(0.f, snew[(size_t)b*NCN + k] + o);
        float so = s[(size_t)b*NCN + k];
        s[(size_t)b*NCN + k] = sf;
        float d = so - sf;
        ds2 += d * d;
    }
    for (int i = tk; i < NV; i += 16) {
        float o = outb[(size_t)b*NOUTP + NCN + i];
        float lf = lamn[(size_t)b*NV + i] + o;
        float lo = lam[(size_t)b*NV + i];
        lam[(size_t)b*NV + i] = lf;
        float d = lo - lf;
        dl2 += d * d;
    }
    redS[tm][tk] = ds2;
    redL[tm][tk] = dl2;
    __syncthreads();
    if (tk == 0) {
        float a = 0.f, l = 0.f;
        for (int q = 0; q < 16; ++q) { a += redS[tm][q]; l += redL[tm][q]; }
        fx[b] = sqrtf(l) + sqrtf(a);
    }
}

// ---------------------------------------------------------------------------
// Fused GRU cell (round-13 config): tile 64 x 128 x 3 gates, 512 thr (8 waves
// = 2m x 4n), 2-buffer LDS 64KB -> 2 blocks/CU. hi+lo B-reuse pairing.
#define GRUF_STEP(NSLOT, BUFI) do {                                              \
    char* Ah_ = lds + (BUFI) * 32768;                                            \
    char* Al_ = Ah_ + 4096;                                                      \
    char* Bb_ = Ah_ + 8192;                                                      \
    const int srow = lane & 15;                                                  \
    const int ksl = lane >> 4;                                                   \
    short8v ah[2], al[2];                                                        \
    _Pragma("unroll")                                                            \
    for (int fm = 0; fm < 2; ++fm) {                                             \
        int rr = wm * 32 + fm * 16 + srow;                                       \
        int off = rr * 64 + ((ksl ^ ((rr >> 1) & 3)) << 4);                      \
        ah[fm] = *(const short8v*)(Ah_ + off);                                   \
        al[fm] = *(const short8v*)(Al_ + off);                                   \
    }                                                                            \
    _Pragma("unroll")                                                            \
    for (int fn = 0; fn < 2; ++fn) {                                             \
        int rb = wn * 32 + fn * 16 + srow;                                       \
        int boff = rb * 64 + ((ksl ^ ((rb >> 1) & 3)) << 4);                     \
        short8v bfr = *(const short8v*)(Bb_ + boff);                             \
        short8v bfz = *(const short8v*)(Bb_ + 8192 + boff);                      \
        short8v bfn = *(const short8v*)(Bb_ + 16384 + boff);                     \
        _Pragma("unroll")                                                        \
        for (int fm = 0; fm < 2; ++fm) {                                         \
            acc[0][fn][fm] = __builtin_amdgcn_mfma_f32_16x16x32_bf16(ah[fm], bfr, acc[0][fn][fm], 0, 0, 0); \
            acc[0][fn][fm] = __builtin_amdgcn_mfma_f32_16x16x32_bf16(al[fm], bfr, acc[0][fn][fm], 0, 0, 0); \
            acc[1][fn][fm] = __builtin_amdgcn_mfma_f32_16x16x32_bf16(ah[fm], bfz, acc[1][fn][fm], 0, 0, 0); \
            acc[1][fn][fm] = __builtin_amdgcn_mfma_f32_16x16x32_bf16(al[fm], bfz, acc[1][fn][fm], 0, 0, 0); \
            acc[NSLOT][fn][fm] = __builtin_amdgcn_mfma_f32_16x16x32_bf16(ah[fm], bfn, acc[NSLOT][fn][fm], 0, 0, 0); \
            acc[NSLOT][fn][fm] = __builtin_amdgcn_mfma_f32_16x16x32_bf16(al[fm], bfn, acc[NSLOT][fn][fm], 0, 0, 0); \
        }                                                                        \
    }                                                                            \
} while (0)

__global__ __launch_bounds__(512) void k_gruf(
        const u16* __restrict__ act,   // [NB][KCAT]: r filled + h_cur
        const u16* __restrict__ Wc,    // [3*1024][KWC]
        const float* __restrict__ bih, const float* __restrict__ bhh,
        u16* __restrict__ actn) {      // h_new -> h-section
    __shared__ char lds[65536];        // 2 x (A_hi 4K + A_lo 4K + B 24K)
    const int t = threadIdx.x;
    const int lane = t & 63;
    const int wid = t >> 6;          // 0..7
    const int wm = wid >> 2;         // 0..1: 32-row band
    const int wn = wid & 3;          // 0..3: 32-col band per gate
    const int bid = blockIdx.x;
    const int xcd = bid & 7;
    const int slot = bid >> 3;       // 0..63
    const int m0 = (xcd * 8 + (slot & 7)) * 64;
    const int n0 = (slot >> 3) * 128;

    f32x4 acc[4][2][2];
    #pragma unroll
    for (int i = 0; i < 4; ++i)
        #pragma unroll
        for (int j = 0; j < 2; ++j)
            #pragma unroll
            for (int k = 0; k < 2; ++k) {
                f32x4 z = {0.f, 0.f, 0.f, 0.f};
                acc[i][j][k] = z;
            }

    auto stage = [&](int step, int buf) {   // 4 gl16 per thread
        char* Ah_ = lds + buf * 32768;
        char* Al_ = Ah_ + 4096;
        char* Bb_ = Ah_ + 8192;
        const int hiOff = (step < NSTEP_R) ? step * 32 : step * 32 + 1088;
        const int loOff = hiOff + ((step < NSTEP_R) ? 1088 : 1024);
        const int wOff = step * 32;
        {
            int rr = (wid & 3) * 16 + (lane >> 2);     // 0..63
            int kq = ((lane & 3) ^ ((rr >> 1) & 3)) << 3;
            if (wid < 4)
                gl16(act + (size_t)(m0 + rr) * KCAT + hiOff + kq, Ah_ + (wid & 3) * 1024);
            else
                gl16(act + (size_t)(m0 + rr) * KCAT + loOff + kq, Al_ + (wid & 3) * 1024);
        }
        #pragma unroll
        for (int j = 0; j < 3; ++j) {
            int cb = wid * 3 + j;              // 0..23
            int rbg = cb * 16 + (lane >> 2);   // 0..383
            int kq = ((lane & 3) ^ ((rbg >> 1) & 3)) << 3;
            gl16(Wc + (size_t)((rbg >> 7) * 1024 + n0 + (rbg & 127)) * KWC + wOff + kq,
                 Bb_ + cb * 1024);
        }
    };

    stage(0, 0);
    __syncthreads();
    int cur = 0;
    for (int step = 0; step < NSTEP_R; ++step) {       // r-part: n-gate -> i_n
        stage(step + 1, cur ^ 1);
        GRUF_STEP(2, cur);
        __syncthreads();
        cur ^= 1;
    }
    for (int step = NSTEP_R; step < NSTEPS; ++step) {  // h-part: n-gate -> h_n
        if (step + 1 < NSTEPS) stage(step + 1, cur ^ 1);
        GRUF_STEP(3, cur);
        __syncthreads();
        cur ^= 1;
    }

    #pragma unroll
    for (int fn = 0; fn < 2; ++fn) {
        const int jj = n0 + wn * 32 + fn * 16 + (lane & 15);
        const float bir = bih[jj],        bhr = bhh[jj];
        const float biz = bih[1024 + jj], bhz = bhh[1024 + jj];
        const float bin = bih[2048 + jj], bhn = bhh[2048 + jj];
        #pragma unroll
        for (int fm = 0; fm < 2; ++fm) {
            #pragma unroll
            for (int rg = 0; rg < 4; ++rg) {
                int m = m0 + wm * 32 + fm * 16 + (lane >> 4) * 4 + rg;
                float rz = acc[0][fn][fm][rg];
                float zz = acc[1][fn][fm][rg];
                float inn = acc[2][fn][fm][rg];
                float hnn = acc[3][fn][fm][rg];
                float rgate = 1.f / (1.f + expf(-(rz + bir + bhr)));
                float zgate = 1.f / (1.f + expf(-(zz + biz + bhz)));
                float ngate = tanhf(inn + bin + rgate * (hnn + bhn));
                size_t base = (size_t)m * KCAT + HOFF;
                float hv = b2f(act[base + jj]) + b2f(act[base + HIDD + jj]);
                float hnew = (1.f - zgate) * ngate + zgate * hv;
                u16 nh = f2b(hnew);
                actn[base + jj] = nh;
                actn[base + HIDD + jj] = f2b(hnew - b2f(nh));
            }
        }
    }
}

// out = h_new @ W_out^T + b_out; tile 64 x 128, grid (64,3), 2-buf 32KB.
__global__ __launch_bounds__(512) void k_outp(
        const u16* __restrict__ act, const u16* __restrict__ Wo,
        const float* __restrict__ bo, float* __restrict__ outb) {
    __shared__ char lds[32768];        // 2 x (A_hi 4K + A_lo 4K + B 8K)
    const int t = threadIdx.x;
    const int lane = t & 63;
    const int wid = t >> 6;
    const int wm = wid >> 2;           // 0..1
    const int wn = wid & 3;            // 0..3
    const int m0 = blockIdx.x * 64;
    const int n0 = blockIdx.y * 128;
    f32x4 acc[2][2];
    #pragma unroll
    for (int i = 0; i < 2; ++i)
        #pragma unroll
        for (int j = 0; j < 2; ++j) {
            f32x4 z = {0.f, 0.f, 0.f, 0.f};
            acc[i][j] = z;
        }

    auto stage = [&](int step, int buf) {   // 2 gl16 per thread
        char* Ah_ = lds + buf * 16384;
        char* Al_ = Ah_ + 4096;
        char* Bb_ = Ah_ + 8192;
        {
            int rr = (wid & 3) * 16 + (lane >> 2);     // 0..63
            int kq = ((lane & 3) ^ ((rr >> 1) & 3)) << 3;
            if (wid < 4)
                gl16(act + (size_t)(m0 + rr) * KCAT + HOFF + step * 32 + kq,
                     Ah_ + (wid & 3) * 1024);
            else
                gl16(act + (size_t)(m0 + rr) * KCAT + HOFF + HIDD + step * 32 + kq,
                     Al_ + (wid & 3) * 1024);
        }
        {
            int rb = wid * 16 + (lane >> 2);           // 0..127
            int kq = ((lane & 3) ^ ((rb >> 1) & 3)) << 3;
            gl16(Wo + (size_t)(n0 + rb) * KWO + step * 32 + kq, Bb_ + wid * 1024);
        }
    };

    stage(0, 0);
    __syncthreads();
    int cur = 0;
    for (int step = 0; step < 32; ++step) {
        if (step + 1 < 32) stage(step + 1, cur ^ 1);
        {
            char* Ah_ = lds + cur * 16384;
            char* Al_ = Ah_ + 4096;
            char* Bb_ = Ah_ + 8192;
            const int srow = lane & 15;
            const int ksl = lane >> 4;
            short8v ah[2], al[2];
            #pragma unroll
            for (int fm = 0; fm < 2; ++fm) {
                int rr = wm * 32 + fm * 16 + srow;
                int off = rr * 64 + ((ksl ^ ((rr >> 1) & 3)) << 4);
                ah[fm] = *(const short8v*)(Ah_ + off);
                al[fm] = *(const short8v*)(Al_ + off);
            }
            #pragma unroll
            for (int fn = 0; fn < 2; ++fn) {
                int rb = wn * 32 + fn * 16 + srow;
                int boff = rb * 64 + ((ksl ^ ((rb >> 1) & 3)) << 4);
                short8v bf = *(const short8v*)(Bb_ + boff);
                #pragma unroll
                for (int fm = 0; fm < 2; ++fm) {
                    acc[fn][fm] = __builtin_amdgcn_mfma_f32_16x16x32_bf16(ah[fm], bf, acc[fn][fm], 0, 0, 0);
                    acc[fn][fm] = __builtin_amdgcn_mfma_f32_16x16x32_bf16(al[fm], bf, acc[fn][fm], 0, 0, 0);
                }
            }
        }
        __syncthreads();
        cur ^= 1;
    }
    #pragma unroll
    for (int fn = 0; fn < 2; ++fn) {
        int n = n0 + wn * 32 + fn * 16 + (lane & 15);
        if (n < NOUTD) {
            float bb = bo[n];
            #pragma unroll
            for (int fm = 0; fm < 2; ++fm) {
                #pragma unroll
                for (int rg = 0; rg < 4; ++rg) {
                    int m = m0 + wm * 32 + fm * 16 + (lane >> 4) * 4 + rg;
                    outb[(size_t)m * NOUTP + n] = acc[fn][fm][rg] + bb;
                }
            }
        }
    }
}

// ---------------------------------------------------------------------------
extern "C" void kernel_launch(void* const* d_in, const int* in_sizes, int n_in,
                              void* d_out, int out_size, void* d_ws, size_t ws_size,
                              hipStream_t stream) {
    const float* lamda_init = (const float*)d_in[0];
    // d_in[1] = s_init (unused: multiplied by 0 in reference)
    const float* h0    = (const float*)d_in[2];
    const float* H     = (const float*)d_in[3];
    const float* g     = (const float*)d_in[4];
    const float* C     = (const float*)d_in[5];
    const float* c     = (const float*)d_in[6];
    const float* W_ih  = (const float*)d_in[7];
    const float* b_ih  = (const float*)d_in[8];
    const float* W_hh  = (const float*)d_in[9];
    const float* b_hh  = (const float*)d_in[10];
    const float* W_out = (const float*)d_in[11];
    const float* b_out = (const float*)d_in[12];

    float* out    = (float*)d_out;
    float* xi_out = out;                       // [B,120]
    float* primal = out + (size_t)NB*NV;       // [8,B]
    float* fixedo = primal + (size_t)NITER*NB; // [8,B]
    float* qpres  = fixedo + (size_t)NITER*NB; // [8,B]

    char* wp = (char*)d_ws;
    auto alloc = [&](size_t bytes) {
        void* p = (void*)wp;
        wp += (bytes + 255) & ~(size_t)255;
        return p;
    };
    float* Amat  = (float*)alloc(NV*NV*4);
    float* A0m   = (float*)alloc(NV*NV*4);
    float* Qinv  = (float*)alloc(NV*NV*4);
    float* Qinv0 = (float*)alloc(NV*NV*4);
    float* CTg   = (float*)alloc((size_t)NV*NCN*4);
    float* s0v   = (float*)alloc(NCN*4);
    float* sbuf  = (float*)alloc((size_t)NB*NCN*4);
    float* snew  = (float*)alloc((size_t)NB*NCN*4);
    float* lam   = (float*)alloc((size_t)NB*NV*4);
    float* lamn  = (float*)alloc((size_t)NB*NV*4);
    float* xib   = (float*)alloc((size_t)NB*NV*4);
    float* Yb    = (float*)alloc((size_t)NB*NV*4);
    float* wb    = (float*)alloc(NB*4);
    float* outb  = (float*)alloc((size_t)NB*NOUTP*4);
    u16* actA    = (u16*)alloc((size_t)NB*KCAT*2);
    u16* actB    = (u16*)alloc((size_t)NB*KCAT*2);
    u16* Wcat    = (u16*)alloc((size_t)3072*KWC*2);
    u16* Wopk    = (u16*)alloc((size_t)NOUTP*KWO*2);
    float* Gpart = (float*)alloc((size_t)NPART*NV*NV*4);
    float* vpart = (float*)alloc((size_t)NPART*NV*4);
    float* Spart = (float*)alloc(NPART*4);
    double* Gfin  = (double*)alloc(NV*NV*8);
    double* vfin  = (double*)alloc(NV*8);
    double* Sfin  = (double*)alloc(8);

    k_buildA<<<dim3(NV, 2), dim3(128), 0, stream>>>(H, C, Amat, A0m);
    k_buildCT<<<dim3(NV), dim3(256), 0, stream>>>(C, CTg);
    k_invert<<<dim3(2), dim3(1024), 0, stream>>>(Amat, A0m, Qinv, Qinv0);
    k_s0<<<dim3(1), dim3(256), 0, stream>>>(Qinv0, g, C, c, s0v);
    k_init<<<dim3(NB/8), dim3(256), 0, stream>>>(s0v, lamda_init, sbuf, lam);
    k_packWcat<<<dim3(3072), dim3(256), 0, stream>>>(W_ih, W_hh, Wcat);
    k_packWo<<<dim3(NOUTP), dim3(256), 0, stream>>>(W_out, Wopk);
    k_packH<<<dim3(NB), dim3(256), 0, stream>>>(h0, actA);

    u16* hc = actA;
    u16* hn2 = actB;
    for (int it = 0; it < NITER; ++it) {
        k_xiproj<<<dim3(NB/XB), dim3(1024), 0, stream>>>(sbuf, lam, C, CTg, c, g, Qinv, H,
                                                         xib, Yb, wb, snew, lamn, hc,
                                                         primal + (size_t)it*NB);
        k_qp_part<<<dim3(NPART), dim3(256), 0, stream>>>(xib, wb, Gpart, vpart, Spart);
        k_qp_red<<<dim3((NV*NV + 255)/256), dim3(256), 0, stream>>>(Gpart, vpart, Spart, Gfin, vfin, Sfin);
        k_gruf<<<dim3(512), dim3(512), 0, stream>>>(hc, Wcat, b_ih, b_hh, hn2);
        k_outp<<<dim3(64, 3), dim3(512), 0, stream>>>(hn2, Wopk, b_out, outb);
        k_tail<<<dim3(NB/16), dim3(256), 0, stream>>>(Yb, Gfin, vfin, Sfin,
                                                      qpres + (size_t)it*NB,
                                                      snew, lamn, outb, sbuf, lam,
                                                      fixedo + (size_t)it*NB);
        u16* tmp = hc; hc = hn2; hn2 = tmp;
    }
    hipMemcpyAsync(xi_out, xib, (size_t)NB*NV*sizeof(float), hipMemcpyDeviceToDevice, stream);
}